// Round 2
// 1173.906 us; speedup vs baseline: 1.2278x; 1.2278x over previous
//
#include <hip/hip_runtime.h>
#include <hip/hip_bf16.h>
#include <hip/hip_fp16.h>

typedef long long i64;
typedef unsigned short u16;
typedef __attribute__((ext_vector_type(8))) short short8;
typedef __attribute__((ext_vector_type(8))) _Float16 half8;
typedef __attribute__((ext_vector_type(4))) float f32x4;

__device__ __forceinline__ float sigf(float x){ return 1.f/(1.f + __expf(-x)); }
__device__ __forceinline__ u16 f2bu(float v){
  union{ __hip_bfloat16 h; u16 u; } cv; cv.h = __float2bfloat16(v); return cv.u;
}
__device__ __forceinline__ u16 f2hu(float v){
  union{ _Float16 h; u16 u; } cv; cv.h = (_Float16)v; return cv.u;
}

// ---------------- f32 -> bf16 vectorized convert ----------------
__global__ void f2b(const float* __restrict__ in, u16* __restrict__ outp, long n){
  long i = ((long)blockIdx.x*256 + threadIdx.x)*4;
  if (i < n){
    float4 v = *(const float4*)(in + i);
    outp[i]   = f2bu(v.x); outp[i+1] = f2bu(v.y);
    outp[i+2] = f2bu(v.z); outp[i+3] = f2bu(v.w);
  }
}

// ---------------- per-layer weight pool convert (11 arrays, fixed sizes) ----------------
__global__ void f2b_wpool(const float* __restrict__ w0, const float* __restrict__ w1,
                          const float* __restrict__ w2, const float* __restrict__ w3,
                          const float* __restrict__ w4, const float* __restrict__ w5,
                          const float* __restrict__ w6, const float* __restrict__ w7,
                          const float* __restrict__ w8, const float* __restrict__ w9,
                          const float* __restrict__ w10, u16* __restrict__ pool){
  long i = ((long)blockIdx.x*256 + threadIdx.x)*4;
  if (i >= 8257536) return;
  const float* src; long rel;
  if      (i <  294912){ src=w0;  rel=i; }
  else if (i <  589824){ src=w1;  rel=i-294912; }
  else if (i < 1179648){ src=w2;  rel=i-589824; }
  else if (i < 2949120){ src=w3;  rel=i-1179648; }
  else if (i < 3538944){ src=w4;  rel=i-2949120; }
  else if (i < 3833856){ src=w5;  rel=i-3538944; }
  else if (i < 4128768){ src=w6;  rel=i-3833856; }
  else if (i < 4423680){ src=w7;  rel=i-4128768; }
  else if (i < 6782976){ src=w8;  rel=i-4423680; }
  else if (i < 7077888){ src=w9;  rel=i-6782976; }
  else                 { src=w10; rel=i-7077888; }
  float4 v = *(const float4*)(src + rel);
  pool[i]   = f2bu(v.x); pool[i+1] = f2bu(v.y);
  pool[i+2] = f2bu(v.z); pool[i+3] = f2bu(v.w);
}

// ---------------- LayerNorm over rows (no affine) ----------------
__global__ __launch_bounds__(256) void ln_rows(const float* __restrict__ x,
                                               float* __restrict__ y, int D){
  long base = (long)blockIdx.x * D;
  int t = threadIdx.x;
  float s = 0.f, ss = 0.f;
  for (int i = t; i < D; i += 256){ float v = x[base+i]; s += v; ss += v*v; }
  __shared__ float r0[256], r1[256];
  r0[t] = s; r1[t] = ss; __syncthreads();
  for (int off = 128; off > 0; off >>= 1){
    if (t < off){ r0[t] += r0[t+off]; r1[t] += r1[t+off]; }
    __syncthreads();
  }
  float mean = r0[0]/D;
  float var  = r1[0]/D - mean*mean;
  float rstd = rsqrtf(var + 1e-5f);
  for (int i = t; i < D; i += 256) y[base+i] = (x[base+i]-mean)*rstd;
}

// ---------------- y_bf = x * w[col] ----------------
__global__ void scale_cols_bf(const float* __restrict__ x, const float* __restrict__ w,
                              u16* __restrict__ y, int D, long n){
  long i = (long)blockIdx.x*256 + threadIdx.x;
  if (i < n) y[i] = f2bu(x[i] * w[i % D]);
}

// ---------------- a2_bf = sigmoid(P1*AN + P2) ----------------
__global__ void adaln_combine_bf(const float* __restrict__ P1, const float* __restrict__ AN,
                                 const float* __restrict__ P2, u16* __restrict__ outb, long n){
  long i = (long)blockIdx.x*256 + threadIdx.x;
  if (i < n) outb[i] = f2bu(sigf(P1[i]*AN[i] + P2[i]));
}

// ---------------- register-resident zln: Zp = (ln(z)*pw+pb)@bwT + bb ----------------
__global__ __launch_bounds__(256) void zln2(const float* __restrict__ z,
    const float* __restrict__ pw, const float* __restrict__ pb,
    const float* __restrict__ bw, const float* __restrict__ bbias,
    float* __restrict__ out){
  i64 p = (i64)blockIdx.x*256 + threadIdx.x;
  const float4* zr = (const float4*)(z + p*64);
  float v[64];
  float s = 0.f, ss = 0.f;
#pragma unroll
  for (int i = 0; i < 16; i++){
    float4 q = zr[i];
    v[4*i] = q.x; v[4*i+1] = q.y; v[4*i+2] = q.z; v[4*i+3] = q.w;
  }
#pragma unroll
  for (int c = 0; c < 64; c++){ s += v[c]; ss = fmaf(v[c], v[c], ss); }
  float m = s*(1.f/64.f);
  float var = ss*(1.f/64.f) - m*m;
  float r = rsqrtf(var + 1e-5f);
#pragma unroll
  for (int c = 0; c < 64; c++) v[c] = (v[c]-m)*r*pw[c] + pb[c];
  float4 o[4];
  float* of = (float*)o;
#pragma unroll
  for (int mm = 0; mm < 16; mm++){
    float acc = bbias[mm];
#pragma unroll
    for (int c = 0; c < 64; c++) acc = fmaf(v[c], bw[mm*64+c], acc);
    of[mm] = acc;
  }
  float4* op = (float4*)(out + p*16);
#pragma unroll
  for (int i = 0; i < 4; i++) op[i] = o[i];
}

// ---------------- per-row softmax stats: (max, 1/sum(exp)) ----------------
__global__ __launch_bounds__(256) void rowstat(const float* __restrict__ sc,
                                               float2* __restrict__ st){
  long base = (long)blockIdx.x * 1024;
  const float4* row = (const float4*)(sc + base);
  int t = threadIdx.x;
  float4 v = row[t];
  float mx = fmaxf(fmaxf(v.x,v.y), fmaxf(v.z,v.w));
  for (int off = 32; off > 0; off >>= 1) mx = fmaxf(mx, __shfl_down(mx, off));
  __shared__ float sm[4], ssum[4];
  int wv = t >> 6, ln = t & 63;
  if (ln == 0) sm[wv] = mx;
  __syncthreads();
  mx = fmaxf(fmaxf(sm[0],sm[1]), fmaxf(sm[2],sm[3]));
  float s = __expf(v.x-mx)+__expf(v.y-mx)+__expf(v.z-mx)+__expf(v.w-mx);
  for (int off = 32; off > 0; off >>= 1) s += __shfl_down(s, off);
  if (ln == 0) ssum[wv] = s;
  __syncthreads();
  if (t == 0) st[blockIdx.x] = make_float2(mx, 1.f/(ssum[0]+ssum[1]+ssum[2]+ssum[3]));
}

// ---------------- V transpose: kvg fp32 [h][x][144]+48 -> Vt fp16 [h][48][1024] ----------------
__global__ __launch_bounds__(256) void vtrans(const float* __restrict__ kvg,
                                              u16* __restrict__ vt){
  int h = blockIdx.x, x0 = blockIdx.y*64;
  __shared__ u16 tile[48][65];
  int t = threadIdx.x;
  for (int idx = t; idx < 64*48; idx += 256){
    int xx = idx/48, c = idx%48;
    tile[c][xx] = f2hu(kvg[(i64)h*147456 + (i64)(x0+xx)*144 + 48 + c]);
  }
  __syncthreads();
  for (int idx = t; idx < 48*64; idx += 256){
    int c = idx>>6, xx = idx&63;
    vt[(i64)h*49152 + (i64)c*1024 + x0 + xx] = tile[c][xx];
  }
}

// ---------------- MFMA fp16 A·V: o[m,c] = sig(g[m,c]) * Σ_k P[k][m]·V[k][c] ----------------
// P staged transposed in LDS with softmax applied inline (exp(v-mx)*invden).
// Output written directly as bf16 to ogated_bf [h][m][48].
__global__ __launch_bounds__(256) void av_gemm(
    const float* __restrict__ P,      // fp32 raw scores [h][1024 k][1024 m]
    const float2* __restrict__ st,    // [h*1024] (rowmax, 1/sum)
    const u16* __restrict__ Vt,       // fp16 [h][48][1024 k]
    const float* __restrict__ kvg,    // fp32, gate at +96, [h][m][144]
    u16* __restrict__ Ob)             // bf16 out [h][m][48]
{
  __shared__ __align__(16) u16 Asm[64*40];
  __shared__ __align__(16) u16 Bsm[64*40];
  int t = threadIdx.x;
  int h = blockIdx.z;
  int m0 = blockIdx.y*64;
  const float* Pp = P + (i64)h*1048576;
  const float2* stp = st + (i64)h*1024;
  const u16* Vp = Vt + (i64)h*49152;
  int lane = t & 63, wv = t >> 6;
  int la = lane & 15, quad = lane >> 4;
  int moff = (wv >> 1)*32, noff = (wv & 1)*32;
  int mcol = t & 63;                 // A staging: m within tile (coalesced global read)
  int kr0  = (t >> 6)*2;             // A staging: even-k start per wave
  int srow = t >> 2, skc = (t & 3)*8; // B staging
  f32x4 acc[2][2] = {{{0.f,0.f,0.f,0.f},{0.f,0.f,0.f,0.f}},
                     {{0.f,0.f,0.f,0.f},{0.f,0.f,0.f,0.f}}};
  for (int k0 = 0; k0 < 1024; k0 += 32){
    // A: Asm[m][k] = fp16( exp(P[k][m]-mx[k]) * invden[k] ), pairs packed as u32
#pragma unroll
    for (int kk = kr0; kk < 32; kk += 8){
      float2 sa = stp[k0+kk];
      float2 sb = stp[k0+kk+1];
      float va = Pp[(i64)(k0+kk  )*1024 + m0 + mcol];
      float vb = Pp[(i64)(k0+kk+1)*1024 + m0 + mcol];
      unsigned int pa = f2hu(__expf(va - sa.x) * sa.y);
      unsigned int pb = f2hu(__expf(vb - sb.x) * sb.y);
      *(unsigned int*)&Asm[mcol*40 + kk] = pa | (pb << 16);
    }
    // B: Vt rows (c), K contiguous; rows >= 48 zero
    uint4 bv = make_uint4(0,0,0,0);
    if (srow < 48) bv = *(const uint4*)(Vp + (i64)srow*1024 + k0 + skc);
    *(uint4*)&Bsm[srow*40 + skc] = bv;
    __syncthreads();
    half8 af0 = *(const half8*)&Asm[(moff      + la)*40 + quad*8];
    half8 af1 = *(const half8*)&Asm[(moff + 16 + la)*40 + quad*8];
    half8 bf0 = *(const half8*)&Bsm[(noff      + la)*40 + quad*8];
    half8 bf1 = *(const half8*)&Bsm[(noff + 16 + la)*40 + quad*8];
    acc[0][0] = __builtin_amdgcn_mfma_f32_16x16x32_f16(af0, bf0, acc[0][0], 0,0,0);
    acc[0][1] = __builtin_amdgcn_mfma_f32_16x16x32_f16(af0, bf1, acc[0][1], 0,0,0);
    acc[1][0] = __builtin_amdgcn_mfma_f32_16x16x32_f16(af1, bf0, acc[1][0], 0,0,0);
    acc[1][1] = __builtin_amdgcn_mfma_f32_16x16x32_f16(af1, bf1, acc[1][1], 0,0,0);
    __syncthreads();
  }
#pragma unroll
  for (int i = 0; i < 2; i++)
#pragma unroll
   for (int j = 0; j < 2; j++)
#pragma unroll
    for (int r = 0; r < 4; r++){
      int gm = m0 + moff + 16*i + quad*4 + r;
      int gn = noff + 16*j + la;
      if (gn < 48){
        float g = kvg[(i64)h*147456 + (i64)gm*144 + 96 + gn];
        float v = sigf(g) * acc[i][j][r];
        Ob[(i64)h*49152 + (i64)gm*48 + gn] = f2bu(v);
      }
    }
}

// ---------------- bb_bf = silu(h1)*h2 ----------------
__global__ void silu_mul_bf(const float* __restrict__ h, u16* __restrict__ bb, long n){
  long i = (long)blockIdx.x*256 + threadIdx.x;
  if (i < n){
    long tt = i/1536, c = i%1536;
    float h1 = h[tt*3072 + c], h2 = h[tt*3072 + 1536 + c];
    bb[i] = f2bu(h1*sigf(h1)*h2);
  }
}

// ---------------- a_next = sig(gate)*attnmm + sig(sg*trb) ----------------
__global__ void final_combine(const float* __restrict__ attnmm, const float* __restrict__ gate,
                              const float* __restrict__ sg, const float* __restrict__ trb,
                              float* __restrict__ a_cur, float* __restrict__ outp, long n){
  long i = (long)blockIdx.x*256 + threadIdx.x;
  if (i < n){
    float v = sigf(gate[i])*attnmm[i] + sigf(sg[i]*trb[i]);
    a_cur[i] = v;
    if (outp) outp[i] = v;
  }
}

// ---------------- bf16 MFMA GEMM: C(M,N) = A(M,K)·B(N,K)^T, batched/strided ----------------
template<int EPI>
__global__ __launch_bounds__(256) void gbt(
    const u16* __restrict__ A, i64 lda, i64 sbA,
    const u16* __restrict__ B, i64 ldb, i64 sbB,
    float* __restrict__ C, i64 ldc, i64 sbC,
    u16* __restrict__ Cbf,
    const float* __restrict__ bias,
    int K, float alpha)
{
  __shared__ __align__(16) u16 Asm[64*40];
  __shared__ __align__(16) u16 Bsm[64*40];
  int t = threadIdx.x;
  int bz = blockIdx.z;
  int m0 = blockIdx.y*64, n0 = blockIdx.x*64;
  int srow = t >> 2, skc = (t & 3)*8;
  const u16* Ar = A + (i64)bz*sbA + (i64)(m0+srow)*lda + skc;
  const u16* Br = B + (i64)bz*sbB + (i64)(n0+srow)*ldb + skc;
  int lane = t & 63, wv = t >> 6;
  int la = lane & 15, quad = lane >> 4;
  int moff = (wv >> 1)*32, noff = (wv & 1)*32;
  f32x4 acc[2][2] = {{{0.f,0.f,0.f,0.f},{0.f,0.f,0.f,0.f}},
                     {{0.f,0.f,0.f,0.f},{0.f,0.f,0.f,0.f}}};
  for (int k0 = 0; k0 < K; k0 += 32){
    uint4 av, bv;
    if (k0 + skc < K){
      av = *(const uint4*)(Ar + k0);
      bv = *(const uint4*)(Br + k0);
    } else {
      av = make_uint4(0,0,0,0); bv = av;
    }
    *(uint4*)&Asm[srow*40 + skc] = av;
    *(uint4*)&Bsm[srow*40 + skc] = bv;
    __syncthreads();
    short8 af0 = *(const short8*)&Asm[(moff      + la)*40 + quad*8];
    short8 af1 = *(const short8*)&Asm[(moff + 16 + la)*40 + quad*8];
    short8 bf0 = *(const short8*)&Bsm[(noff      + la)*40 + quad*8];
    short8 bf1 = *(const short8*)&Bsm[(noff + 16 + la)*40 + quad*8];
    acc[0][0] = __builtin_amdgcn_mfma_f32_16x16x32_bf16(af0, bf0, acc[0][0], 0,0,0);
    acc[0][1] = __builtin_amdgcn_mfma_f32_16x16x32_bf16(af0, bf1, acc[0][1], 0,0,0);
    acc[1][0] = __builtin_amdgcn_mfma_f32_16x16x32_bf16(af1, bf0, acc[1][0], 0,0,0);
    acc[1][1] = __builtin_amdgcn_mfma_f32_16x16x32_bf16(af1, bf1, acc[1][1], 0,0,0);
    __syncthreads();
  }
  float* Cb = C ? C + (i64)bz*sbC : nullptr;
  u16* Cb2 = Cbf ? Cbf + (i64)bz*sbC : nullptr;
#pragma unroll
  for (int i = 0; i < 2; i++)
#pragma unroll
   for (int j = 0; j < 2; j++)
#pragma unroll
    for (int r = 0; r < 4; r++){
      int gm = m0 + moff + 16*i + quad*4 + r;
      int gn = n0 + noff + 16*j + la;
      i64 idx = (i64)gm*ldc + gn;
      float v = acc[i][j][r];
      if (EPI == 1){
        Cb[idx] += alpha*v;
      } else {
        if (bias) v += bias[gn];
        if (Cb)  Cb[idx]  = v;
        if (Cb2) Cb2[idx] = f2bu(v);
      }
    }
}

extern "C" void kernel_launch(void* const* d_in, const int* in_sizes, int n_in,
                              void* d_out, int out_size, void* d_ws, size_t ws_size,
                              hipStream_t stream){
  const float* a_in   = (const float*)d_in[0];
  const float* s_in   = (const float*)d_in[1];
  const float* z_in   = (const float*)d_in[2];
  const float* attn_sn_w = (const float*)d_in[3];
  const float* attn_pb_w = (const float*)d_in[4];
  const float* attn_pb_b = (const float*)d_in[5];
  const float* attn_pnb_w= (const float*)d_in[6];
  const float* pair_w = (const float*)d_in[7];
  const float* pair_b = (const float*)d_in[8];
  const float* q_w    = (const float*)d_in[9];
  const float* q_b    = (const float*)d_in[10];
  const float* kvg_w  = (const float*)d_in[11];
  const float* bias_w = (const float*)d_in[12];
  const float* bias_b = (const float*)d_in[13];
  const float* ao_w   = (const float*)d_in[14];
  const float* out_w  = (const float*)d_in[15];
  const float* out_b  = (const float*)d_in[16];
  const float* tr_sn_w= (const float*)d_in[17];
  const float* tr_pb_w= (const float*)d_in[18];
  const float* tr_pb_b= (const float*)d_in[19];
  const float* tr_pnb_w=(const float*)d_in[20];
  const float* tr_a_w = (const float*)d_in[21];
  const float* tr_s_w = (const float*)d_in[22];
  const float* tr_s_b = (const float*)d_in[23];
  const float* tr_b_w = (const float*)d_in[24];

  // -------- workspace layout --------
  float* ws      = (float*)d_ws;
  float* scores  = ws;                     // 16777216 f32 (H,S,S); also hbuf/trb/sgate reuse
  float* hbuf    = scores;                 // 3145728 (after AV consumed scores)
  float* trb     = scores + 3145728;       // 786432
  float* sgate   = scores + 3932160;       // 786432
  float* a_cur   = ws + 16777216;          // 786432
  float* AN      = a_cur + 786432;         // 786432
  float* SN0     = AN + 786432;            // 393216
  float* P1      = SN0 + 393216;           // 786432
  float* P2      = P1 + 786432;            // 786432
  float* kvg     = P2 + 786432;            // 2359296
  float* ogated  = kvg + 2359296;          // 786432 (now: Vt fp16 + rowstats)
  float* attnmm  = ogated + 786432;        // 786432
  float* gatebuf = attnmm + 786432;        // 786432
  u16* wpool     = (u16*)(gatebuf + 786432);   // 8257536 bf16 (per-layer weights)
  u16* SNw_bf    = wpool + 8257536;        // 393216
  u16* s_bf      = SNw_bf + 393216;        // 393216
  u16* a2bf      = s_bf + 393216;          // 786432
  u16* qproj_bf  = a2bf + 786432;          // 786432
  u16* kvg_bf    = qproj_bf + 786432;      // 2359296
  u16* ogated_bf = kvg_bf + 2359296;       // 786432
  u16* bbuf_bf   = ogated_bf + 786432;     // 1572864

  // reuse dead ogated fp32 region: Vt fp16 (786432 u16) + rowstats (16384 float2)
  u16*    Vt_h   = (u16*)ogated;
  float2* rstats = (float2*)(ogated + 393216);

  // pool offsets (bf16 elems)
  const i64 OFF_PB=0, OFF_PNB=294912, OFF_Q=589824, OFF_KVG=1179648, OFF_AO=2949120,
            OFF_OUT=3538944, OFF_TPB=3833856, OFF_TPNB=4128768, OFF_TRA=4423680,
            OFF_TRS=6782976, OFF_TRB=7077888;

  f2b<<<384,256,0,stream>>>(s_in, s_bf, 393216);
  ln_rows<<<1024,256,0,stream>>>(s_in, SN0, 384);   // LN(s), layer-independent

  for (int l = 0; l < 2; l++){
    f2b_wpool<<<8064,256,0,stream>>>(
        attn_pb_w + (i64)l*294912, attn_pnb_w + (i64)l*294912,
        q_w + (i64)l*589824, kvg_w + (i64)l*1769472, ao_w + (i64)l*589824,
        out_w + (i64)l*294912, tr_pb_w + (i64)l*294912, tr_pnb_w + (i64)l*294912,
        tr_a_w + (i64)l*2359296, tr_s_w + (i64)l*294912, tr_b_w + (i64)l*1179648, wpool);

    ln_rows<<<1024,256,0,stream>>>(l == 0 ? a_in : a_cur, AN, 768);

    // ---- AttentionPairBias: adaln ----
    scale_cols_bf<<<1536,256,0,stream>>>(SN0, attn_sn_w + l*384, SNw_bf, 384, 393216);
    gbt<0><<<dim3(12,16,1),256,0,stream>>>(SNw_bf,384,0, wpool+OFF_PB,384,0,
        P1,768,0, nullptr, attn_pb_b + l*768, 384, 1.f);
    gbt<0><<<dim3(12,16,1),256,0,stream>>>(SNw_bf,384,0, wpool+OFF_PNB,384,0,
        P2,768,0, nullptr, nullptr, 384, 1.f);
    adaln_combine_bf<<<3072,256,0,stream>>>(P1, AN, P2, a2bf, 786432);

    // ---- projections (bf16 MFMA) ----
    gbt<0><<<dim3(12,16,1),256,0,stream>>>(a2bf,768,0, wpool+OFF_Q,768,0,
        nullptr,768,0, qproj_bf, q_b + l*768, 768, 1.f);
    gbt<0><<<dim3(36,16,1),256,0,stream>>>(a2bf,768,0, wpool+OFF_KVG,768,0,
        kvg,2304,0, kvg_bf, nullptr, 768, 1.f);

    // ---- pair bias: Zp into scores (flat identity with bmat) ----
    zln2<<<4096,256,0,stream>>>(z_in, pair_w + l*64, pair_b + l*64,
        bias_w + l*1024, bias_b + l*16, scores);

    // ---- scores[h,x,y] += K[x]·Q[y]/48 (MFMA, batched over heads) ----
    gbt<1><<<dim3(16,16,16),256,0,stream>>>(kvg_bf,144,147456, qproj_bf,48,49152,
        scores,1024,1048576, nullptr, nullptr, 48, 1.f/48.f);

    // ---- softmax stats + V transpose + fused MFMA A^T·V with gating ----
    rowstat<<<16384,256,0,stream>>>(scores, rstats);
    vtrans<<<dim3(16,16),256,0,stream>>>(kvg, Vt_h);
    av_gemm<<<dim3(1,16,16),256,0,stream>>>(scores, rstats, Vt_h, kvg, ogated_bf);

    gbt<0><<<dim3(12,16,1),256,0,stream>>>(ogated_bf,768,0, wpool+OFF_AO,768,0,
        attnmm,768,0, nullptr, nullptr, 768, 1.f);
    gbt<0><<<dim3(12,16,1),256,0,stream>>>(s_bf,384,0, wpool+OFF_OUT,384,0,
        gatebuf,768,0, nullptr, out_b + l*768, 384, 1.f);

    // ---- ConditionedTransitionBlock ----
    scale_cols_bf<<<1536,256,0,stream>>>(SN0, tr_sn_w + l*384, SNw_bf, 384, 393216);
    gbt<0><<<dim3(12,16,1),256,0,stream>>>(SNw_bf,384,0, wpool+OFF_TPB,384,0,
        P1,768,0, nullptr, tr_pb_b + l*768, 384, 1.f);
    gbt<0><<<dim3(12,16,1),256,0,stream>>>(SNw_bf,384,0, wpool+OFF_TPNB,384,0,
        P2,768,0, nullptr, nullptr, 384, 1.f);
    adaln_combine_bf<<<3072,256,0,stream>>>(P1, AN, P2, a2bf, 786432);

    gbt<0><<<dim3(48,16,1),256,0,stream>>>(a2bf,768,0, wpool+OFF_TRA,768,0,
        hbuf,3072,0, nullptr, nullptr, 768, 1.f);
    silu_mul_bf<<<6144,256,0,stream>>>(hbuf, bbuf_bf, 1572864);
    gbt<0><<<dim3(12,16,1),256,0,stream>>>(bbuf_bf,1536,0, wpool+OFF_TRB,1536,0,
        trb,768,0, nullptr, nullptr, 1536, 1.f);
    gbt<0><<<dim3(12,16,1),256,0,stream>>>(s_bf,384,0, wpool+OFF_TRS,384,0,
        sgate,768,0, nullptr, tr_s_b + l*768, 384, 1.f);

    final_combine<<<3072,256,0,stream>>>(attnmm, gatebuf, sgate, trb, a_cur,
        (l==1) ? (float*)d_out : (float*)nullptr, 786432);
  }
}

// Round 3
// 924.538 us; speedup vs baseline: 1.5589x; 1.2697x over previous
//
#include <hip/hip_runtime.h>
#include <hip/hip_bf16.h>
#include <hip/hip_fp16.h>

typedef long long i64;
typedef unsigned short u16;
typedef __attribute__((ext_vector_type(8))) short short8;
typedef __attribute__((ext_vector_type(8))) _Float16 half8;
typedef __attribute__((ext_vector_type(4))) float f32x4;

__device__ __forceinline__ float sigf(float x){ return 1.f/(1.f + __expf(-x)); }
__device__ __forceinline__ u16 f2bu(float v){
  union{ __hip_bfloat16 h; u16 u; } cv; cv.h = __float2bfloat16(v); return cv.u;
}
__device__ __forceinline__ u16 f2hu(float v){
  union{ _Float16 h; u16 u; } cv; cv.h = (_Float16)v; return cv.u;
}
__device__ __forceinline__ float h2f(u16 u){
  union{ u16 u; _Float16 h; } cv; cv.u = u; return (float)cv.h;
}

// ---------------- f32 -> bf16 vectorized convert ----------------
__global__ void f2b(const float* __restrict__ in, u16* __restrict__ outp, long n){
  long i = ((long)blockIdx.x*256 + threadIdx.x)*4;
  if (i < n){
    float4 v = *(const float4*)(in + i);
    outp[i]   = f2bu(v.x); outp[i+1] = f2bu(v.y);
    outp[i+2] = f2bu(v.z); outp[i+3] = f2bu(v.w);
  }
}

// ---------------- per-layer weight pool convert (11 arrays, reordered pool) ----------------
// pool order: PB | PNB | Q | KVG | AO | OUT | TRS | TPB | TPNB | TRA | TRB
__global__ void f2b_wpool(const float* __restrict__ w0, const float* __restrict__ w1,
                          const float* __restrict__ w2, const float* __restrict__ w3,
                          const float* __restrict__ w4, const float* __restrict__ w5,
                          const float* __restrict__ w6, const float* __restrict__ w7,
                          const float* __restrict__ w8, const float* __restrict__ w9,
                          const float* __restrict__ w10, u16* __restrict__ pool){
  long i = ((long)blockIdx.x*256 + threadIdx.x)*4;
  if (i >= 8257536) return;
  const float* src; long rel;
  if      (i <  294912){ src=w0;  rel=i; }
  else if (i <  589824){ src=w1;  rel=i-294912; }
  else if (i < 1179648){ src=w2;  rel=i-589824; }
  else if (i < 2949120){ src=w3;  rel=i-1179648; }
  else if (i < 3538944){ src=w4;  rel=i-2949120; }
  else if (i < 3833856){ src=w5;  rel=i-3538944; }
  else if (i < 4128768){ src=w6;  rel=i-3833856; }
  else if (i < 4423680){ src=w7;  rel=i-4128768; }
  else if (i < 4718592){ src=w8;  rel=i-4423680; }
  else if (i < 7077888){ src=w9;  rel=i-4718592; }
  else                 { src=w10; rel=i-7077888; }
  float4 v = *(const float4*)(src + rel);
  pool[i]   = f2bu(v.x); pool[i+1] = f2bu(v.y);
  pool[i+2] = f2bu(v.z); pool[i+3] = f2bu(v.w);
}

// ---------------- LayerNorm over rows (no affine) ----------------
__global__ __launch_bounds__(256) void ln_rows(const float* __restrict__ x,
                                               float* __restrict__ y, int D){
  long base = (long)blockIdx.x * D;
  int t = threadIdx.x;
  float s = 0.f, ss = 0.f;
  for (int i = t; i < D; i += 256){ float v = x[base+i]; s += v; ss += v*v; }
  __shared__ float r0[256], r1[256];
  r0[t] = s; r1[t] = ss; __syncthreads();
  for (int off = 128; off > 0; off >>= 1){
    if (t < off){ r0[t] += r0[t+off]; r1[t] += r1[t+off]; }
    __syncthreads();
  }
  float mean = r0[0]/D;
  float var  = r1[0]/D - mean*mean;
  float rstd = rsqrtf(var + 1e-5f);
  for (int i = t; i < D; i += 256) y[base+i] = (x[base+i]-mean)*rstd;
}

// ---------------- SNw2[t][0:384]=SN0*w_at, [384:768]=SN0*w_tr ----------------
__global__ void scale2(const float* __restrict__ SN0, const float* __restrict__ w_at,
                       const float* __restrict__ w_tr, u16* __restrict__ y){
  long i = (long)blockIdx.x*256 + threadIdx.x;
  if (i < 786432){
    long tt = i/768, c = i%768;
    float v = (c < 384) ? SN0[tt*384+c]*w_at[c] : SN0[tt*384+c-384]*w_tr[c-384];
    y[i] = f2bu(v);
  }
}

// ---------------- a2_bf from fused P buffer [1024][1536]: sig((P1+b)*AN + P2) ----------------
__global__ void adaln2(const float* __restrict__ Pf, const float* __restrict__ AN,
                       const float* __restrict__ b, u16* __restrict__ outb){
  long i = (long)blockIdx.x*256 + threadIdx.x;
  if (i < 786432){
    long tt = i/768, c = i%768;
    float p1 = Pf[tt*1536 + c] + b[c];
    float p2 = Pf[tt*1536 + 768 + c];
    outb[i] = f2bu(sigf(p1*AN[i] + p2));
  }
}

// ---------------- combined gate biases: gbias[l][0:768]=out_b, [768:1536]=tr_s_b ----------------
__global__ void catbias(const float* __restrict__ ob, const float* __restrict__ tb,
                        float* __restrict__ g){
  int i = blockIdx.x*256 + threadIdx.x;
  if (i < 3072){
    int l = i/1536, c = i%1536;
    g[i] = (c < 768) ? ob[l*768+c] : tb[l*768+c-768];
  }
}

// ---------------- zprep: fold LN-affine into proj weights ----------------
// cw[l][mm][c] = pw[l][c]*bw[l][mm][c]; cb[l][mm] = bb[l][mm] + sum_c pb[l][c]*bw[l][mm][c]
__global__ void zprep(const float* __restrict__ pw, const float* __restrict__ pb,
                      const float* __restrict__ bw, const float* __restrict__ bb,
                      float* __restrict__ cw, float* __restrict__ cb){
  int i = blockIdx.x*256 + threadIdx.x;
  if (i < 2048){
    int l = i/1024, c = i%64;
    cw[i] = pw[l*64+c]*bw[i];
  } else if (i < 2080){
    int t = i - 2048;
    int l = t/16, mm = t%16;
    float acc = bb[l*16+mm];
    for (int c = 0; c < 64; c++) acc += pb[l*64+c]*bw[l*1024+mm*64+c];
    cb[t] = acc;
  }
}

// ---------------- zln_dual: both layers' pair bias from one z read, fp16 out ----------------
// Zp[l] flat layout (x,y,16h) fp16 — raw-reshape view as [h][x][y] matches torch.
__global__ __launch_bounds__(256) void zln_dual(const float* __restrict__ z,
    const float* __restrict__ cw, const float* __restrict__ cb,
    u16* __restrict__ Zp){
  i64 p = (i64)blockIdx.x*256 + threadIdx.x;
  const float4* zr = (const float4*)(z + p*64);
  float v[64];
  float s = 0.f, ss = 0.f;
#pragma unroll
  for (int i = 0; i < 16; i++){
    float4 q = zr[i];
    v[4*i] = q.x; v[4*i+1] = q.y; v[4*i+2] = q.z; v[4*i+3] = q.w;
  }
#pragma unroll
  for (int c = 0; c < 64; c++){ s += v[c]; ss = fmaf(v[c], v[c], ss); }
  float m = s*(1.f/64.f);
  float var = ss*(1.f/64.f) - m*m;
  float r = rsqrtf(var + 1e-5f);
#pragma unroll
  for (int c = 0; c < 64; c++) v[c] = (v[c]-m)*r;
  for (int l = 0; l < 2; l++){
    unsigned int o[8];
#pragma unroll
    for (int mm = 0; mm < 16; mm++){
      float acc = cb[l*16+mm];
      const float* w = cw + l*1024 + mm*64;
#pragma unroll
      for (int c = 0; c < 64; c++) acc = fmaf(v[c], w[c], acc);
      unsigned int hv = f2hu(acc);
      if (mm & 1) o[mm>>1] |= hv << 16; else o[mm>>1] = hv;
    }
    uint4* op = (uint4*)(Zp + (i64)l*16777216 + p*16);
    op[0] = make_uint4(o[0],o[1],o[2],o[3]);
    op[1] = make_uint4(o[4],o[5],o[6],o[7]);
  }
}

// ---------------- per-row softmax stats: (max, 1/sum(exp)) ----------------
__global__ __launch_bounds__(256) void rowstat(const float* __restrict__ sc,
                                               float2* __restrict__ st){
  long base = (long)blockIdx.x * 1024;
  const float4* row = (const float4*)(sc + base);
  int t = threadIdx.x;
  float4 v = row[t];
  float mx = fmaxf(fmaxf(v.x,v.y), fmaxf(v.z,v.w));
  for (int off = 32; off > 0; off >>= 1) mx = fmaxf(mx, __shfl_down(mx, off));
  __shared__ float sm[4], ssum[4];
  int wv = t >> 6, ln = t & 63;
  if (ln == 0) sm[wv] = mx;
  __syncthreads();
  mx = fmaxf(fmaxf(sm[0],sm[1]), fmaxf(sm[2],sm[3]));
  float s = __expf(v.x-mx)+__expf(v.y-mx)+__expf(v.z-mx)+__expf(v.w-mx);
  for (int off = 32; off > 0; off >>= 1) s += __shfl_down(s, off);
  if (ln == 0) ssum[wv] = s;
  __syncthreads();
  if (t == 0) st[blockIdx.x] = make_float2(mx, 1.f/(ssum[0]+ssum[1]+ssum[2]+ssum[3]));
}

// ---------------- V transpose: kvg fp32 [h][x][144]+48 -> Vt fp16 [h][48][1024] ----------------
__global__ __launch_bounds__(256) void vtrans(const float* __restrict__ kvg,
                                              u16* __restrict__ vt){
  int h = blockIdx.x, x0 = blockIdx.y*64;
  __shared__ u16 tile[48][65];
  int t = threadIdx.x;
  for (int idx = t; idx < 64*48; idx += 256){
    int xx = idx/48, c = idx%48;
    tile[c][xx] = f2hu(kvg[(i64)h*147456 + (i64)(x0+xx)*144 + 48 + c]);
  }
  __syncthreads();
  for (int idx = t; idx < 48*64; idx += 256){
    int c = idx>>6, xx = idx&63;
    vt[(i64)h*49152 + (i64)c*1024 + x0 + xx] = tile[c][xx];
  }
}

// ---------------- MFMA fp16 A·V (software-pipelined): o = sig(g)*Σ_k P[k][m]·V[k][c] ----------------
__global__ __launch_bounds__(256) void av_gemm(
    const float* __restrict__ P,      // fp32 raw scores [h][1024 k][1024 m]
    const float2* __restrict__ st,    // [h*1024] (rowmax, 1/sum)
    const u16* __restrict__ Vt,       // fp16 [h][48][1024 k]
    const float* __restrict__ kvg,    // fp32, gate at +96, [h][m][144]
    u16* __restrict__ Ob)             // bf16 out [h][m][48]
{
  __shared__ __align__(16) u16 Asm[64*40];
  __shared__ __align__(16) u16 Bsm[64*40];
  int t = threadIdx.x;
  int h = blockIdx.z;
  int m0 = blockIdx.y*64;
  const float* Pp = P + (i64)h*1048576;
  const float2* stp = st + (i64)h*1024;
  const u16* Vp = Vt + (i64)h*49152;
  int lane = t & 63, wv = t >> 6;
  int la = lane & 15, quad = lane >> 4;
  int moff = (wv >> 1)*32, noff = (wv & 1)*32;
  int mcol = t & 63;
  int kr0  = (t >> 6)*2;
  int srow = t >> 2, skc = (t & 3)*8;
  f32x4 acc[2][2] = {{{0.f,0.f,0.f,0.f},{0.f,0.f,0.f,0.f}},
                     {{0.f,0.f,0.f,0.f},{0.f,0.f,0.f,0.f}}};
  float va[4], vb[4];
  float2 sa[4], sb[4];
  uint4 bv;
  // prologue load: tile 0
#pragma unroll
  for (int q = 0; q < 4; q++){
    int kk = kr0 + q*8;
    sa[q] = stp[kk]; sb[q] = stp[kk+1];
    va[q] = Pp[(i64)kk*1024 + m0 + mcol];
    vb[q] = Pp[(i64)(kk+1)*1024 + m0 + mcol];
  }
  bv = make_uint4(0,0,0,0);
  if (srow < 48) bv = *(const uint4*)(Vp + (i64)srow*1024 + skc);
  for (int it = 0; it < 32; it++){
    // pack current tile into LDS (exp-normalize inline)
#pragma unroll
    for (int q = 0; q < 4; q++){
      int kk = kr0 + q*8;
      unsigned int pa = f2hu(__expf(va[q] - sa[q].x) * sa[q].y);
      unsigned int pb = f2hu(__expf(vb[q] - sb[q].x) * sb[q].y);
      *(unsigned int*)&Asm[mcol*40 + kk] = pa | (pb << 16);
    }
    *(uint4*)&Bsm[srow*40 + skc] = bv;
    __syncthreads();
    // prefetch next tile into regs (overlaps with MFMA below)
    if (it < 31){
      int k0 = (it+1)*32;
#pragma unroll
      for (int q = 0; q < 4; q++){
        int kk = kr0 + q*8;
        sa[q] = stp[k0+kk]; sb[q] = stp[k0+kk+1];
        va[q] = Pp[(i64)(k0+kk)*1024 + m0 + mcol];
        vb[q] = Pp[(i64)(k0+kk+1)*1024 + m0 + mcol];
      }
      bv = make_uint4(0,0,0,0);
      if (srow < 48) bv = *(const uint4*)(Vp + (i64)srow*1024 + k0 + skc);
    }
    half8 af0 = *(const half8*)&Asm[(moff      + la)*40 + quad*8];
    half8 af1 = *(const half8*)&Asm[(moff + 16 + la)*40 + quad*8];
    half8 bf0 = *(const half8*)&Bsm[(noff      + la)*40 + quad*8];
    half8 bf1 = *(const half8*)&Bsm[(noff + 16 + la)*40 + quad*8];
    acc[0][0] = __builtin_amdgcn_mfma_f32_16x16x32_f16(af0, bf0, acc[0][0], 0,0,0);
    acc[0][1] = __builtin_amdgcn_mfma_f32_16x16x32_f16(af0, bf1, acc[0][1], 0,0,0);
    acc[1][0] = __builtin_amdgcn_mfma_f32_16x16x32_f16(af1, bf0, acc[1][0], 0,0,0);
    acc[1][1] = __builtin_amdgcn_mfma_f32_16x16x32_f16(af1, bf1, acc[1][1], 0,0,0);
    __syncthreads();
  }
#pragma unroll
  for (int i = 0; i < 2; i++)
#pragma unroll
   for (int j = 0; j < 2; j++)
#pragma unroll
    for (int r = 0; r < 4; r++){
      int gm = m0 + moff + 16*i + quad*4 + r;
      int gn = noff + 16*j + la;
      if (gn < 48){
        float g = kvg[(i64)h*147456 + (i64)gm*144 + 96 + gn];
        float v = sigf(g) * acc[i][j][r];
        Ob[(i64)h*49152 + (i64)gm*48 + gn] = f2bu(v);
      }
    }
}

// ---------------- bb_bf = silu(h1)*h2 ----------------
__global__ void silu_mul_bf(const float* __restrict__ h, u16* __restrict__ bb, long n){
  long i = (long)blockIdx.x*256 + threadIdx.x;
  if (i < n){
    long tt = i/1536, c = i%1536;
    float h1 = h[tt*3072 + c], h2 = h[tt*3072 + 1536 + c];
    bb[i] = f2bu(h1*sigf(h1)*h2);
  }
}

// ---------------- bf16 MFMA GEMM: C(M,N) = A(M,K)·B(N,K)^T, batched/strided ----------------
// EPI 0: r(+bias[n]) -> C (f32, optional) and/or Cbf
// EPI 1: C = alpha*r + fp16 X1[bz*sbC + idx]   (pair-bias add, no RMW)
// EPI 3: C = sigf(X1f[gm*1536+gn]) * r          (attn gate fused into AO)
// EPI 4: res = X1f[gm*768+gn] + sigf(X2f[gm*1536+gn]*r); C=res; C2?=res  (final combine)
template<int EPI>
__global__ __launch_bounds__(256) void gbt(
    const u16* __restrict__ A, i64 lda, i64 sbA,
    const u16* __restrict__ B, i64 ldb, i64 sbB,
    float* __restrict__ C, i64 ldc, i64 sbC,
    u16* __restrict__ Cbf,
    const float* __restrict__ bias,
    const void* __restrict__ X1, const void* __restrict__ X2,
    float* __restrict__ C2,
    int K, float alpha)
{
  __shared__ __align__(16) u16 Asm[64*40];
  __shared__ __align__(16) u16 Bsm[64*40];
  int t = threadIdx.x;
  int bz = blockIdx.z;
  int m0 = blockIdx.y*64, n0 = blockIdx.x*64;
  int srow = t >> 2, skc = (t & 3)*8;
  const u16* Ar = A + (i64)bz*sbA + (i64)(m0+srow)*lda + skc;
  const u16* Br = B + (i64)bz*sbB + (i64)(n0+srow)*ldb + skc;
  int lane = t & 63, wv = t >> 6;
  int la = lane & 15, quad = lane >> 4;
  int moff = (wv >> 1)*32, noff = (wv & 1)*32;
  f32x4 acc[2][2] = {{{0.f,0.f,0.f,0.f},{0.f,0.f,0.f,0.f}},
                     {{0.f,0.f,0.f,0.f},{0.f,0.f,0.f,0.f}}};
  for (int k0 = 0; k0 < K; k0 += 32){
    uint4 av, bv;
    if (k0 + skc < K){
      av = *(const uint4*)(Ar + k0);
      bv = *(const uint4*)(Br + k0);
    } else {
      av = make_uint4(0,0,0,0); bv = av;
    }
    *(uint4*)&Asm[srow*40 + skc] = av;
    *(uint4*)&Bsm[srow*40 + skc] = bv;
    __syncthreads();
    short8 af0 = *(const short8*)&Asm[(moff      + la)*40 + quad*8];
    short8 af1 = *(const short8*)&Asm[(moff + 16 + la)*40 + quad*8];
    short8 bf0 = *(const short8*)&Bsm[(noff      + la)*40 + quad*8];
    short8 bf1 = *(const short8*)&Bsm[(noff + 16 + la)*40 + quad*8];
    acc[0][0] = __builtin_amdgcn_mfma_f32_16x16x32_bf16(af0, bf0, acc[0][0], 0,0,0);
    acc[0][1] = __builtin_amdgcn_mfma_f32_16x16x32_bf16(af0, bf1, acc[0][1], 0,0,0);
    acc[1][0] = __builtin_amdgcn_mfma_f32_16x16x32_bf16(af1, bf0, acc[1][0], 0,0,0);
    acc[1][1] = __builtin_amdgcn_mfma_f32_16x16x32_bf16(af1, bf1, acc[1][1], 0,0,0);
    __syncthreads();
  }
  float* Cb = C ? C + (i64)bz*sbC : nullptr;
  u16* Cb2 = Cbf ? Cbf + (i64)bz*sbC : nullptr;
  const u16* zp = (EPI == 1) ? (const u16*)X1 + (i64)bz*sbC : nullptr;
#pragma unroll
  for (int i = 0; i < 2; i++)
#pragma unroll
   for (int j = 0; j < 2; j++)
#pragma unroll
    for (int r = 0; r < 4; r++){
      int gm = m0 + moff + 16*i + quad*4 + r;
      int gn = n0 + noff + 16*j + la;
      i64 idx = (i64)gm*ldc + gn;
      float v = acc[i][j][r];
      if (EPI == 1){
        Cb[idx] = alpha*v + h2f(zp[idx]);
      } else if (EPI == 3){
        const float* g = (const float*)X1;
        Cb[idx] = sigf(g[(i64)gm*1536 + gn]) * v;
      } else if (EPI == 4){
        const float* am = (const float*)X1;
        const float* sg = (const float*)X2;
        float res = am[(i64)gm*768 + gn] + sigf(sg[(i64)gm*1536 + gn] * v);
        Cb[idx] = res;
        if (C2) C2[idx] = res;
      } else {
        if (bias) v += bias[gn];
        if (Cb)  Cb[idx]  = v;
        if (Cb2) Cb2[idx] = f2bu(v);
      }
    }
}

extern "C" void kernel_launch(void* const* d_in, const int* in_sizes, int n_in,
                              void* d_out, int out_size, void* d_ws, size_t ws_size,
                              hipStream_t stream){
  const float* a_in   = (const float*)d_in[0];
  const float* s_in   = (const float*)d_in[1];
  const float* z_in   = (const float*)d_in[2];
  const float* attn_sn_w = (const float*)d_in[3];
  const float* attn_pb_w = (const float*)d_in[4];
  const float* attn_pb_b = (const float*)d_in[5];
  const float* attn_pnb_w= (const float*)d_in[6];
  const float* pair_w = (const float*)d_in[7];
  const float* pair_b = (const float*)d_in[8];
  const float* q_w    = (const float*)d_in[9];
  const float* q_b    = (const float*)d_in[10];
  const float* kvg_w  = (const float*)d_in[11];
  const float* bias_w = (const float*)d_in[12];
  const float* bias_b = (const float*)d_in[13];
  const float* ao_w   = (const float*)d_in[14];
  const float* out_w  = (const float*)d_in[15];
  const float* out_b  = (const float*)d_in[16];
  const float* tr_sn_w= (const float*)d_in[17];
  const float* tr_pb_w= (const float*)d_in[18];
  const float* tr_pb_b= (const float*)d_in[19];
  const float* tr_pnb_w=(const float*)d_in[20];
  const float* tr_a_w = (const float*)d_in[21];
  const float* tr_s_w = (const float*)d_in[22];
  const float* tr_s_b = (const float*)d_in[23];
  const float* tr_b_w = (const float*)d_in[24];

  // -------- workspace layout (f32 elems from base; total ~193 MB, ws is ~1 GiB) --------
  float* ws      = (float*)d_ws;
  float* scores  = ws;                     // 16777216 f32 [h][x][y]; region reused post-attn
  float* hbuf    = scores;                 // + 0       : 3145728  (TRA out)
  float* gfused  = scores + 3145728;       // + 3145728 : 1572864  ([1024][1536] gate|sgate)
  float* attnmm  = scores + 4718592;       // + 4718592 : 786432   (gated AO out)
  float* a_cur   = ws + 16777216;          // 786432
  float* AN      = a_cur + 786432;         // 786432
  float* SN0     = AN + 786432;            // 393216
  float* Pfused  = SN0 + 393216;           // 1572864 ([1024][1536])
  float* kvg     = Pfused + 1572864;       // 2359296
  float* vaux    = kvg + 2359296;          // 786432 (Vt fp16 + rowstats)
  float* gbias   = vaux + 786432;          // 3072
  float* zcw     = gbias + 3072;           // 2048
  float* zcb     = zcw + 2048;             // 32 (+pad)
  u16* wpool     = (u16*)(zcb + 64);       // 8257536
  u16* SNw2_bf   = wpool + 8257536;        // 786432 ([1024][768], attn|tr halves)
  u16* s_bf      = SNw2_bf + 786432;       // 393216
  u16* a2bf      = s_bf + 393216;          // 786432
  u16* qproj_bf  = a2bf + 786432;          // 786432
  u16* kvg_bf    = qproj_bf + 786432;      // 2359296
  u16* ogated_bf = kvg_bf + 2359296;       // 786432
  u16* bbuf_bf   = ogated_bf + 786432;     // 1572864
  u16* Zp2       = bbuf_bf + 1572864;      // 33554432 (fp16 pair bias, both layers)

  u16*    Vt_h   = (u16*)vaux;             // 786432 u16
  float2* rstats = (float2*)(vaux + 393216);

  // pool offsets (bf16 elems) — reordered: PB|PNB|Q|KVG|AO|OUT|TRS|TPB|TPNB|TRA|TRB
  const i64 OFF_PB=0, OFF_Q=589824, OFF_KVG=1179648, OFF_AO=2949120,
            OFF_OUT=3538944, OFF_TPB=4128768, OFF_TRA=4718592, OFF_TRB=7077888;

  f2b<<<384,256,0,stream>>>(s_in, s_bf, 393216);
  ln_rows<<<1024,256,0,stream>>>(s_in, SN0, 384);   // LN(s), layer-independent
  catbias<<<12,256,0,stream>>>(out_b, tr_s_b, gbias);
  zprep<<<9,256,0,stream>>>(pair_w, pair_b, bias_w, bias_b, zcw, zcb);
  zln_dual<<<4096,256,0,stream>>>(z_in, zcw, zcb, Zp2);   // one z read, both layers, fp16

  for (int l = 0; l < 2; l++){
    f2b_wpool<<<8064,256,0,stream>>>(
        attn_pb_w + (i64)l*294912, attn_pnb_w + (i64)l*294912,
        q_w + (i64)l*589824, kvg_w + (i64)l*1769472, ao_w + (i64)l*589824,
        out_w + (i64)l*294912, tr_s_w + (i64)l*294912,
        tr_pb_w + (i64)l*294912, tr_pnb_w + (i64)l*294912,
        tr_a_w + (i64)l*2359296, tr_b_w + (i64)l*1179648, wpool);

    ln_rows<<<1024,256,0,stream>>>(l == 0 ? a_in : a_cur, AN, 768);
    scale2<<<3072,256,0,stream>>>(SN0, attn_sn_w + l*384, tr_sn_w + l*384, SNw2_bf);

    // ---- AttentionPairBias adaln: fused PB|PNB gemm (N=1536) ----
    gbt<0><<<dim3(24,16,1),256,0,stream>>>(SNw2_bf,768,0, wpool+OFF_PB,384,0,
        Pfused,1536,0, nullptr, nullptr, nullptr, nullptr, nullptr, 384, 1.f);
    adaln2<<<3072,256,0,stream>>>(Pfused, AN, attn_pb_b + l*768, a2bf);

    // ---- projections ----
    gbt<0><<<dim3(12,16,1),256,0,stream>>>(a2bf,768,0, wpool+OFF_Q,768,0,
        nullptr,768,0, qproj_bf, q_b + l*768, nullptr, nullptr, nullptr, 768, 1.f);
    gbt<0><<<dim3(36,16,1),256,0,stream>>>(a2bf,768,0, wpool+OFF_KVG,768,0,
        kvg,2304,0, kvg_bf, nullptr, nullptr, nullptr, nullptr, 768, 1.f);

    // ---- scores[h,x,y] = K·Q/48 + Zp_fp16 ----
    gbt<1><<<dim3(16,16,16),256,0,stream>>>(kvg_bf,144,147456, qproj_bf,48,49152,
        scores,1024,1048576, nullptr, nullptr, Zp2 + (i64)l*16777216, nullptr, nullptr,
        48, 1.f/48.f);

    // ---- softmax stats + V^T + fused MFMA A^T·V with gating ----
    rowstat<<<16384,256,0,stream>>>(scores, rstats);
    vtrans<<<dim3(16,16),256,0,stream>>>(kvg, Vt_h);
    av_gemm<<<dim3(1,16,16),256,0,stream>>>(scores, rstats, Vt_h, kvg, ogated_bf);

    // ---- gates: fused OUT|TRS gemm (N=1536) into gfused (scores region now dead) ----
    gbt<0><<<dim3(24,16,1),256,0,stream>>>(s_bf,384,0, wpool+OFF_OUT,384,0,
        gfused,1536,0, nullptr, gbias + l*1536, nullptr, nullptr, nullptr, 384, 1.f);

    // ---- AO gemm with fused attn gate ----
    gbt<3><<<dim3(12,16,1),256,0,stream>>>(ogated_bf,768,0, wpool+OFF_AO,768,0,
        attnmm,768,0, nullptr, nullptr, gfused, nullptr, nullptr, 768, 1.f);

    // ---- ConditionedTransitionBlock: fused TPB|TPNB gemm ----
    gbt<0><<<dim3(24,16,1),256,0,stream>>>(SNw2_bf+384,768,0, wpool+OFF_TPB,384,0,
        Pfused,1536,0, nullptr, nullptr, nullptr, nullptr, nullptr, 384, 1.f);
    adaln2<<<3072,256,0,stream>>>(Pfused, AN, tr_pb_b + l*768, a2bf);

    gbt<0><<<dim3(48,16,1),256,0,stream>>>(a2bf,768,0, wpool+OFF_TRA,768,0,
        hbuf,3072,0, nullptr, nullptr, nullptr, nullptr, nullptr, 768, 1.f);
    silu_mul_bf<<<6144,256,0,stream>>>(hbuf, bbuf_bf, 1572864);

    // ---- TRB gemm with fused final combine: a_cur = attnmm + sig(sgate*trb) ----
    gbt<4><<<dim3(12,16,1),256,0,stream>>>(bbuf_bf,1536,0, wpool+OFF_TRB,1536,0,
        a_cur,768,0, nullptr, nullptr, attnmm, gfused + 768,
        (l==1) ? (float*)d_out : nullptr, 1536, 1.f);
  }
}

// Round 4
// 889.720 us; speedup vs baseline: 1.6199x; 1.0391x over previous
//
#include <hip/hip_runtime.h>
#include <hip/hip_bf16.h>
#include <hip/hip_fp16.h>

typedef long long i64;
typedef unsigned short u16;
typedef __attribute__((ext_vector_type(8))) short short8;
typedef __attribute__((ext_vector_type(8))) _Float16 half8;
typedef __attribute__((ext_vector_type(4))) float f32x4;

__device__ __forceinline__ float sigf(float x){ return 1.f/(1.f + __expf(-x)); }
__device__ __forceinline__ u16 f2bu(float v){
  union{ __hip_bfloat16 h; u16 u; } cv; cv.h = __float2bfloat16(v); return cv.u;
}
__device__ __forceinline__ u16 f2hu(float v){
  union{ _Float16 h; u16 u; } cv; cv.h = (_Float16)v; return cv.u;
}
__device__ __forceinline__ float h2f(u16 u){
  union{ u16 u; _Float16 h; } cv; cv.u = u; return (float)cv.h;
}

// ---------------- f32 -> bf16 vectorized convert ----------------
__global__ void f2b(const float* __restrict__ in, u16* __restrict__ outp, long n){
  long i = ((long)blockIdx.x*256 + threadIdx.x)*4;
  if (i < n){
    float4 v = *(const float4*)(in + i);
    outp[i]   = f2bu(v.x); outp[i+1] = f2bu(v.y);
    outp[i+2] = f2bu(v.z); outp[i+3] = f2bu(v.w);
  }
}

// ---------------- per-layer weight pool convert (11 arrays, reordered pool) ----------------
// pool order: PB | PNB | Q | KVG | AO | OUT | TRS | TPB | TPNB | TRA | TRB
__global__ void f2b_wpool(const float* __restrict__ w0, const float* __restrict__ w1,
                          const float* __restrict__ w2, const float* __restrict__ w3,
                          const float* __restrict__ w4, const float* __restrict__ w5,
                          const float* __restrict__ w6, const float* __restrict__ w7,
                          const float* __restrict__ w8, const float* __restrict__ w9,
                          const float* __restrict__ w10, u16* __restrict__ pool){
  long i = ((long)blockIdx.x*256 + threadIdx.x)*4;
  if (i >= 8257536) return;
  const float* src; long rel;
  if      (i <  294912){ src=w0;  rel=i; }
  else if (i <  589824){ src=w1;  rel=i-294912; }
  else if (i < 1179648){ src=w2;  rel=i-589824; }
  else if (i < 2949120){ src=w3;  rel=i-1179648; }
  else if (i < 3538944){ src=w4;  rel=i-2949120; }
  else if (i < 3833856){ src=w5;  rel=i-3538944; }
  else if (i < 4128768){ src=w6;  rel=i-3833856; }
  else if (i < 4423680){ src=w7;  rel=i-4128768; }
  else if (i < 4718592){ src=w8;  rel=i-4423680; }
  else if (i < 7077888){ src=w9;  rel=i-4718592; }
  else                 { src=w10; rel=i-7077888; }
  float4 v = *(const float4*)(src + rel);
  pool[i]   = f2bu(v.x); pool[i+1] = f2bu(v.y);
  pool[i+2] = f2bu(v.z); pool[i+3] = f2bu(v.w);
}

// ---------------- LayerNorm over rows (no affine) ----------------
__global__ __launch_bounds__(256) void ln_rows(const float* __restrict__ x,
                                               float* __restrict__ y, int D){
  long base = (long)blockIdx.x * D;
  int t = threadIdx.x;
  float s = 0.f, ss = 0.f;
  for (int i = t; i < D; i += 256){ float v = x[base+i]; s += v; ss += v*v; }
  __shared__ float r0[256], r1[256];
  r0[t] = s; r1[t] = ss; __syncthreads();
  for (int off = 128; off > 0; off >>= 1){
    if (t < off){ r0[t] += r0[t+off]; r1[t] += r1[t+off]; }
    __syncthreads();
  }
  float mean = r0[0]/D;
  float var  = r1[0]/D - mean*mean;
  float rstd = rsqrtf(var + 1e-5f);
  for (int i = t; i < D; i += 256) y[base+i] = (x[base+i]-mean)*rstd;
}

// ---------------- SNw2[t][0:384]=SN0*w_at, [384:768]=SN0*w_tr ----------------
__global__ void scale2(const float* __restrict__ SN0, const float* __restrict__ w_at,
                       const float* __restrict__ w_tr, u16* __restrict__ y){
  long i = (long)blockIdx.x*256 + threadIdx.x;
  if (i < 786432){
    long tt = i/768, c = i%768;
    float v = (c < 384) ? SN0[tt*384+c]*w_at[c] : SN0[tt*384+c-384]*w_tr[c-384];
    y[i] = f2bu(v);
  }
}

// ---------------- a2_bf from fused P buffer [1024][1536]: sig((P1+b)*AN + P2) ----------------
__global__ void adaln2(const float* __restrict__ Pf, const float* __restrict__ AN,
                       const float* __restrict__ b, u16* __restrict__ outb){
  long i = (long)blockIdx.x*256 + threadIdx.x;
  if (i < 786432){
    long tt = i/768, c = i%768;
    float p1 = Pf[tt*1536 + c] + b[c];
    float p2 = Pf[tt*1536 + 768 + c];
    outb[i] = f2bu(sigf(p1*AN[i] + p2));
  }
}

// ---------------- combined gate biases: gbias[l][0:768]=out_b, [768:1536]=tr_s_b ----------------
__global__ void catbias(const float* __restrict__ ob, const float* __restrict__ tb,
                        float* __restrict__ g){
  int i = blockIdx.x*256 + threadIdx.x;
  if (i < 3072){
    int l = i/1536, c = i%1536;
    g[i] = (c < 768) ? ob[l*768+c] : tb[l*768+c-768];
  }
}

// ---------------- zprep: fold LN-affine into proj weights, emit fp16 ----------------
// cwh[l*16+mm][c] = fp16(pw[l][c]*bw[l][mm][c]); cb[l*16+mm] = bb + sum_c pb[c]*bw[mm][c]
__global__ void zprep(const float* __restrict__ pw, const float* __restrict__ pb,
                      const float* __restrict__ bw, const float* __restrict__ bb,
                      u16* __restrict__ cwh, float* __restrict__ cb){
  int i = blockIdx.x*256 + threadIdx.x;
  if (i < 2048){
    int l = i/1024, c = i%64;
    cwh[i] = f2hu(pw[l*64+c]*bw[i]);
  } else if (i < 2080){
    int t = i - 2048;
    int l = t/16, mm = t%16;
    float acc = bb[l*16+mm];
    for (int c = 0; c < 64; c++) acc += pb[l*64+c]*bw[l*1024+mm*64+c];
    cb[t] = acc;
  }
}

// ---------------- zln_mfma: LN(z) in regs -> LDS fp16 tile -> MFMA 64->32 proj ----------------
// Zp[l] flat (x,y,16h) fp16 — raw-reshape view as [h][x][y] matches torch.
__global__ __launch_bounds__(256) void zln_mfma(const float* __restrict__ z,
    const u16* __restrict__ Bw,   // fp16 [32][64], row = l*16+mm
    const float* __restrict__ cb, // f32 [32]
    u16* __restrict__ Zp){
  __shared__ __align__(16) u16 Asm[256*72];   // 36 KB A tile; reused for output staging
  __shared__ __align__(16) u16 Bsm[32*72];    // 4.5 KB
  int t = threadIdx.x;
  i64 p0 = (i64)blockIdx.x*256;
  // stage B (32 rows x 64 fp16), 64 threads x 32B
  if (t < 64){
    int row = t >> 1, half = t & 1;
    const uint4* src = (const uint4*)(Bw + row*64 + half*32);
    uint4* dst = (uint4*)&Bsm[row*72 + half*32];
    dst[0]=src[0]; dst[1]=src[1]; dst[2]=src[2]; dst[3]=src[3];
  }
  // load + LN own position (64 channels in regs)
  const float4* zr = (const float4*)(z + (p0 + t)*64);
  float v[64];
  float s = 0.f, ss = 0.f;
#pragma unroll
  for (int i = 0; i < 16; i++){
    float4 q = zr[i];
    v[4*i] = q.x; v[4*i+1] = q.y; v[4*i+2] = q.z; v[4*i+3] = q.w;
  }
#pragma unroll
  for (int c = 0; c < 64; c++){ s += v[c]; ss = fmaf(v[c], v[c], ss); }
  float m = s*(1.f/64.f);
  float var = ss*(1.f/64.f) - m*m;
  float r = rsqrtf(var + 1e-5f);
  // write LN'd row into A tile as fp16 pairs
#pragma unroll
  for (int c = 0; c < 32; c++){
    unsigned int lo = f2hu((v[2*c]  -m)*r);
    unsigned int hi = f2hu((v[2*c+1]-m)*r);
    *(unsigned int*)&Asm[t*72 + 2*c] = lo | (hi << 16);
  }
  __syncthreads();
  // MFMA: per wave M=64 (4 frags), N=32 (2 frags), K=64 (2 chunks)
  int lane = t & 63, wv = t >> 6, la = lane & 15, quad = lane >> 4;
  f32x4 acc[4][2] = {};
#pragma unroll
  for (int kc = 0; kc < 2; kc++){
    half8 af[4], bf[2];
#pragma unroll
    for (int i = 0; i < 4; i++)
      af[i] = *(const half8*)&Asm[(64*wv + 16*i + la)*72 + kc*32 + quad*8];
#pragma unroll
    for (int j = 0; j < 2; j++)
      bf[j] = *(const half8*)&Bsm[(16*j + la)*72 + kc*32 + quad*8];
#pragma unroll
    for (int i = 0; i < 4; i++)
#pragma unroll
      for (int j = 0; j < 2; j++)
        acc[i][j] = __builtin_amdgcn_mfma_f32_16x16x32_f16(af[i], bf[j], acc[i][j], 0,0,0);
  }
  __syncthreads();
  // stage results into Asm as [pos][32] fp16 (+bias)
#pragma unroll
  for (int i = 0; i < 4; i++)
#pragma unroll
   for (int j = 0; j < 2; j++)
#pragma unroll
    for (int rr = 0; rr < 4; rr++){
      int row = 64*wv + 16*i + quad*4 + rr;
      int gn = 16*j + la;
      Asm[row*72 + gn] = f2hu(acc[i][j][rr] + cb[gn]);
    }
  __syncthreads();
  // coalesced fp16 writes: layer0 = cols 0..15, layer1 = cols 16..31
  uint4* o0 = (uint4*)(Zp + (p0 + t)*16);
  uint4* o1 = (uint4*)(Zp + 16777216 + (p0 + t)*16);
  o0[0] = *(uint4*)&Asm[t*72];
  o0[1] = *(uint4*)&Asm[t*72 + 8];
  o1[0] = *(uint4*)&Asm[t*72 + 16];
  o1[1] = *(uint4*)&Asm[t*72 + 24];
}

// ---------------- per-row softmax stats: (max, 1/sum(exp)) ----------------
__global__ __launch_bounds__(256) void rowstat(const float* __restrict__ sc,
                                               float2* __restrict__ st){
  long base = (long)blockIdx.x * 1024;
  const float4* row = (const float4*)(sc + base);
  int t = threadIdx.x;
  float4 v = row[t];
  float mx = fmaxf(fmaxf(v.x,v.y), fmaxf(v.z,v.w));
  for (int off = 32; off > 0; off >>= 1) mx = fmaxf(mx, __shfl_down(mx, off));
  __shared__ float sm[4], ssum[4];
  int wv = t >> 6, ln = t & 63;
  if (ln == 0) sm[wv] = mx;
  __syncthreads();
  mx = fmaxf(fmaxf(sm[0],sm[1]), fmaxf(sm[2],sm[3]));
  float s = __expf(v.x-mx)+__expf(v.y-mx)+__expf(v.z-mx)+__expf(v.w-mx);
  for (int off = 32; off > 0; off >>= 1) s += __shfl_down(s, off);
  if (ln == 0) ssum[wv] = s;
  __syncthreads();
  if (t == 0) st[blockIdx.x] = make_float2(mx, 1.f/(ssum[0]+ssum[1]+ssum[2]+ssum[3]));
}

// ---------------- V transpose: kvg fp32 [h][x][144]+48 -> Vt fp16 [h][48][1024] ----------------
__global__ __launch_bounds__(256) void vtrans(const float* __restrict__ kvg,
                                              u16* __restrict__ vt){
  int h = blockIdx.x, x0 = blockIdx.y*64;
  __shared__ u16 tile[48][65];
  int t = threadIdx.x;
  for (int idx = t; idx < 64*48; idx += 256){
    int xx = idx/48, c = idx%48;
    tile[c][xx] = f2hu(kvg[(i64)h*147456 + (i64)(x0+xx)*144 + 48 + c]);
  }
  __syncthreads();
  for (int idx = t; idx < 48*64; idx += 256){
    int c = idx>>6, xx = idx&63;
    vt[(i64)h*49152 + (i64)c*1024 + x0 + xx] = tile[c][xx];
  }
}

// ---------------- MFMA fp16 A·V (software-pipelined): o = sig(g)*Σ_k P[k][m]·V[k][c] ----------------
__global__ __launch_bounds__(256) void av_gemm(
    const float* __restrict__ P,      // fp32 raw scores [h][1024 k][1024 m]
    const float2* __restrict__ st,    // [h*1024] (rowmax, 1/sum)
    const u16* __restrict__ Vt,      // fp16 [h][48][1024 k]
    const float* __restrict__ kvg,    // fp32, gate at +96, [h][m][144]
    u16* __restrict__ Ob)             // bf16 out [h][m][48]
{
  __shared__ __align__(16) u16 Asm[64*40];
  __shared__ __align__(16) u16 Bsm[64*40];
  int t = threadIdx.x;
  int h = blockIdx.z;
  int m0 = blockIdx.y*64;
  const float* Pp = P + (i64)h*1048576;
  const float2* stp = st + (i64)h*1024;
  const u16* Vp = Vt + (i64)h*49152;
  int lane = t & 63, wv = t >> 6;
  int la = lane & 15, quad = lane >> 4;
  int moff = (wv >> 1)*32, noff = (wv & 1)*32;
  int mcol = t & 63;
  int kr0  = (t >> 6)*2;
  int srow = t >> 2, skc = (t & 3)*8;
  f32x4 acc[2][2] = {{{0.f,0.f,0.f,0.f},{0.f,0.f,0.f,0.f}},
                     {{0.f,0.f,0.f,0.f},{0.f,0.f,0.f,0.f}}};
  float va[4], vb[4];
  float2 sa[4], sb[4];
  uint4 bv;
#pragma unroll
  for (int q = 0; q < 4; q++){
    int kk = kr0 + q*8;
    sa[q] = stp[kk]; sb[q] = stp[kk+1];
    va[q] = Pp[(i64)kk*1024 + m0 + mcol];
    vb[q] = Pp[(i64)(kk+1)*1024 + m0 + mcol];
  }
  bv = make_uint4(0,0,0,0);
  if (srow < 48) bv = *(const uint4*)(Vp + (i64)srow*1024 + skc);
  for (int it = 0; it < 32; it++){
#pragma unroll
    for (int q = 0; q < 4; q++){
      int kk = kr0 + q*8;
      unsigned int pa = f2hu(__expf(va[q] - sa[q].x) * sa[q].y);
      unsigned int pb = f2hu(__expf(vb[q] - sb[q].x) * sb[q].y);
      *(unsigned int*)&Asm[mcol*40 + kk] = pa | (pb << 16);
    }
    *(uint4*)&Bsm[srow*40 + skc] = bv;
    __syncthreads();
    if (it < 31){
      int k0 = (it+1)*32;
#pragma unroll
      for (int q = 0; q < 4; q++){
        int kk = kr0 + q*8;
        sa[q] = stp[k0+kk]; sb[q] = stp[k0+kk+1];
        va[q] = Pp[(i64)(k0+kk)*1024 + m0 + mcol];
        vb[q] = Pp[(i64)(k0+kk+1)*1024 + m0 + mcol];
      }
      bv = make_uint4(0,0,0,0);
      if (srow < 48) bv = *(const uint4*)(Vp + (i64)srow*1024 + k0 + skc);
    }
    half8 af0 = *(const half8*)&Asm[(moff      + la)*40 + quad*8];
    half8 af1 = *(const half8*)&Asm[(moff + 16 + la)*40 + quad*8];
    half8 bf0 = *(const half8*)&Bsm[(noff      + la)*40 + quad*8];
    half8 bf1 = *(const half8*)&Bsm[(noff + 16 + la)*40 + quad*8];
    acc[0][0] = __builtin_amdgcn_mfma_f32_16x16x32_f16(af0, bf0, acc[0][0], 0,0,0);
    acc[0][1] = __builtin_amdgcn_mfma_f32_16x16x32_f16(af0, bf1, acc[0][1], 0,0,0);
    acc[1][0] = __builtin_amdgcn_mfma_f32_16x16x32_f16(af1, bf0, acc[1][0], 0,0,0);
    acc[1][1] = __builtin_amdgcn_mfma_f32_16x16x32_f16(af1, bf1, acc[1][1], 0,0,0);
    __syncthreads();
  }
#pragma unroll
  for (int i = 0; i < 2; i++)
#pragma unroll
   for (int j = 0; j < 2; j++)
#pragma unroll
    for (int r = 0; r < 4; r++){
      int gm = m0 + moff + 16*i + quad*4 + r;
      int gn = noff + 16*j + la;
      if (gn < 48){
        float g = kvg[(i64)h*147456 + (i64)gm*144 + 96 + gn];
        float v = sigf(g) * acc[i][j][r];
        Ob[(i64)h*49152 + (i64)gm*48 + gn] = f2bu(v);
      }
    }
}

// ---------------- bb_bf = silu(h1)*h2 ----------------
__global__ void silu_mul_bf(const float* __restrict__ h, u16* __restrict__ bb, long n){
  long i = (long)blockIdx.x*256 + threadIdx.x;
  if (i < n){
    long tt = i/1536, c = i%1536;
    float h1 = h[tt*3072 + c], h2 = h[tt*3072 + 1536 + c];
    bb[i] = f2bu(h1*sigf(h1)*h2);
  }
}

// ---------------- bf16 MFMA GEMM: C(M,N) = A(M,K)·B(N,K)^T, batched/strided ----------------
// EPI 0: r(+bias[n]) -> C (f32, optional) and/or Cbf
// EPI 1: C = alpha*r + fp16 X1[bz*sbC + idx]   (pair-bias add, no RMW)
// EPI 3: C = sigf(X1f[gm*1536+gn]) * r          (attn gate fused into AO)
// EPI 4: res = X1f[gm*768+gn] + sigf(X2f[gm*1536+gn]*r); C=res; C2?=res  (final combine)
template<int EPI>
__global__ __launch_bounds__(256) void gbt(
    const u16* __restrict__ A, i64 lda, i64 sbA,
    const u16* __restrict__ B, i64 ldb, i64 sbB,
    float* __restrict__ C, i64 ldc, i64 sbC,
    u16* __restrict__ Cbf,
    const float* __restrict__ bias,
    const void* __restrict__ X1, const void* __restrict__ X2,
    float* __restrict__ C2,
    int K, float alpha)
{
  __shared__ __align__(16) u16 Asm[64*40];
  __shared__ __align__(16) u16 Bsm[64*40];
  int t = threadIdx.x;
  int bz = blockIdx.z;
  int m0 = blockIdx.y*64, n0 = blockIdx.x*64;
  int srow = t >> 2, skc = (t & 3)*8;
  const u16* Ar = A + (i64)bz*sbA + (i64)(m0+srow)*lda + skc;
  const u16* Br = B + (i64)bz*sbB + (i64)(n0+srow)*ldb + skc;
  int lane = t & 63, wv = t >> 6;
  int la = lane & 15, quad = lane >> 4;
  int moff = (wv >> 1)*32, noff = (wv & 1)*32;
  f32x4 acc[2][2] = {{{0.f,0.f,0.f,0.f},{0.f,0.f,0.f,0.f}},
                     {{0.f,0.f,0.f,0.f},{0.f,0.f,0.f,0.f}}};
  for (int k0 = 0; k0 < K; k0 += 32){
    uint4 av, bv;
    if (k0 + skc < K){
      av = *(const uint4*)(Ar + k0);
      bv = *(const uint4*)(Br + k0);
    } else {
      av = make_uint4(0,0,0,0); bv = av;
    }
    *(uint4*)&Asm[srow*40 + skc] = av;
    *(uint4*)&Bsm[srow*40 + skc] = bv;
    __syncthreads();
    short8 af0 = *(const short8*)&Asm[(moff      + la)*40 + quad*8];
    short8 af1 = *(const short8*)&Asm[(moff + 16 + la)*40 + quad*8];
    short8 bf0 = *(const short8*)&Bsm[(noff      + la)*40 + quad*8];
    short8 bf1 = *(const short8*)&Bsm[(noff + 16 + la)*40 + quad*8];
    acc[0][0] = __builtin_amdgcn_mfma_f32_16x16x32_bf16(af0, bf0, acc[0][0], 0,0,0);
    acc[0][1] = __builtin_amdgcn_mfma_f32_16x16x32_bf16(af0, bf1, acc[0][1], 0,0,0);
    acc[1][0] = __builtin_amdgcn_mfma_f32_16x16x32_bf16(af1, bf0, acc[1][0], 0,0,0);
    acc[1][1] = __builtin_amdgcn_mfma_f32_16x16x32_bf16(af1, bf1, acc[1][1], 0,0,0);
    __syncthreads();
  }
  float* Cb = C ? C + (i64)bz*sbC : nullptr;
  u16* Cb2 = Cbf ? Cbf + (i64)bz*sbC : nullptr;
  const u16* zp = (EPI == 1) ? (const u16*)X1 + (i64)bz*sbC : nullptr;
#pragma unroll
  for (int i = 0; i < 2; i++)
#pragma unroll
   for (int j = 0; j < 2; j++)
#pragma unroll
    for (int r = 0; r < 4; r++){
      int gm = m0 + moff + 16*i + quad*4 + r;
      int gn = n0 + noff + 16*j + la;
      i64 idx = (i64)gm*ldc + gn;
      float v = acc[i][j][r];
      if (EPI == 1){
        Cb[idx] = alpha*v + h2f(zp[idx]);
      } else if (EPI == 3){
        const float* g = (const float*)X1;
        Cb[idx] = sigf(g[(i64)gm*1536 + gn]) * v;
      } else if (EPI == 4){
        const float* am = (const float*)X1;
        const float* sg = (const float*)X2;
        float res = am[(i64)gm*768 + gn] + sigf(sg[(i64)gm*1536 + gn] * v);
        Cb[idx] = res;
        if (C2) C2[idx] = res;
      } else {
        if (bias) v += bias[gn];
        if (Cb)  Cb[idx]  = v;
        if (Cb2) Cb2[idx] = f2bu(v);
      }
    }
}

extern "C" void kernel_launch(void* const* d_in, const int* in_sizes, int n_in,
                              void* d_out, int out_size, void* d_ws, size_t ws_size,
                              hipStream_t stream){
  const float* a_in   = (const float*)d_in[0];
  const float* s_in   = (const float*)d_in[1];
  const float* z_in   = (const float*)d_in[2];
  const float* attn_sn_w = (const float*)d_in[3];
  const float* attn_pb_w = (const float*)d_in[4];
  const float* attn_pb_b = (const float*)d_in[5];
  const float* attn_pnb_w= (const float*)d_in[6];
  const float* pair_w = (const float*)d_in[7];
  const float* pair_b = (const float*)d_in[8];
  const float* q_w    = (const float*)d_in[9];
  const float* q_b    = (const float*)d_in[10];
  const float* kvg_w  = (const float*)d_in[11];
  const float* bias_w = (const float*)d_in[12];
  const float* bias_b = (const float*)d_in[13];
  const float* ao_w   = (const float*)d_in[14];
  const float* out_w  = (const float*)d_in[15];
  const float* out_b  = (const float*)d_in[16];
  const float* tr_sn_w= (const float*)d_in[17];
  const float* tr_pb_w= (const float*)d_in[18];
  const float* tr_pb_b= (const float*)d_in[19];
  const float* tr_pnb_w=(const float*)d_in[20];
  const float* tr_a_w = (const float*)d_in[21];
  const float* tr_s_w = (const float*)d_in[22];
  const float* tr_s_b = (const float*)d_in[23];
  const float* tr_b_w = (const float*)d_in[24];

  // -------- workspace layout (f32 elems from base) --------
  float* ws      = (float*)d_ws;
  float* scores  = ws;                     // 16777216 f32 [h][x][y]; region reused post-attn
  float* hbuf    = scores;                 // + 0       : 3145728  (TRA out)
  float* gfused  = scores + 3145728;       // + 3145728 : 1572864  ([1024][1536] gate|sgate)
  float* attnmm  = scores + 4718592;       // + 4718592 : 786432   (gated AO out)
  float* a_cur   = ws + 16777216;          // 786432
  float* AN      = a_cur + 786432;         // 786432
  float* SN0     = AN + 786432;            // 393216
  float* Pfused  = SN0 + 393216;           // 1572864 ([1024][1536])
  float* kvg     = Pfused + 1572864;       // 2359296
  float* vaux    = kvg + 2359296;          // 786432 (Vt fp16 + rowstats)
  float* gbias   = vaux + 786432;          // 3072
  float* zcw     = gbias + 3072;           // 2048 f32 region (first 1024 used as u16[2048])
  float* zcb     = zcw + 2048;             // 32 (+pad)
  u16* wpool     = (u16*)(zcb + 64);       // 8257536
  u16* SNw2_bf   = wpool + 8257536;        // 786432 ([1024][768], attn|tr halves)
  u16* s_bf      = SNw2_bf + 786432;       // 393216
  u16* a2bf      = s_bf + 393216;          // 786432
  u16* qproj_bf  = a2bf + 786432;          // 786432
  u16* kvg_bf    = qproj_bf + 786432;      // 2359296
  u16* ogated_bf = kvg_bf + 2359296;       // 786432
  u16* bbuf_bf   = ogated_bf + 786432;     // 1572864
  u16* Zp2       = bbuf_bf + 1572864;      // 33554432 (fp16 pair bias, both layers)

  u16*    Vt_h   = (u16*)vaux;             // 786432 u16
  float2* rstats = (float2*)(vaux + 393216);
  u16*    zcwh   = (u16*)zcw;              // fp16 [32][64]

  // pool offsets (bf16 elems) — reordered: PB|PNB|Q|KVG|AO|OUT|TRS|TPB|TPNB|TRA|TRB
  const i64 OFF_PB=0, OFF_Q=589824, OFF_KVG=1179648, OFF_AO=2949120,
            OFF_OUT=3538944, OFF_TPB=4128768, OFF_TRA=4718592, OFF_TRB=7077888;

  f2b<<<384,256,0,stream>>>(s_in, s_bf, 393216);
  ln_rows<<<1024,256,0,stream>>>(s_in, SN0, 384);   // LN(s), layer-independent
  catbias<<<12,256,0,stream>>>(out_b, tr_s_b, gbias);
  zprep<<<9,256,0,stream>>>(pair_w, pair_b, bias_w, bias_b, zcwh, zcb);
  zln_mfma<<<4096,256,0,stream>>>(z_in, zcwh, zcb, Zp2);  // one z read, both layers, fp16

  for (int l = 0; l < 2; l++){
    f2b_wpool<<<8064,256,0,stream>>>(
        attn_pb_w + (i64)l*294912, attn_pnb_w + (i64)l*294912,
        q_w + (i64)l*589824, kvg_w + (i64)l*1769472, ao_w + (i64)l*589824,
        out_w + (i64)l*294912, tr_s_w + (i64)l*294912,
        tr_pb_w + (i64)l*294912, tr_pnb_w + (i64)l*294912,
        tr_a_w + (i64)l*2359296, tr_b_w + (i64)l*1179648, wpool);

    ln_rows<<<1024,256,0,stream>>>(l == 0 ? a_in : a_cur, AN, 768);
    scale2<<<3072,256,0,stream>>>(SN0, attn_sn_w + l*384, tr_sn_w + l*384, SNw2_bf);

    // ---- AttentionPairBias adaln: fused PB|PNB gemm (N=1536) ----
    gbt<0><<<dim3(24,16,1),256,0,stream>>>(SNw2_bf,768,0, wpool+OFF_PB,384,0,
        Pfused,1536,0, nullptr, nullptr, nullptr, nullptr, nullptr, 384, 1.f);
    adaln2<<<3072,256,0,stream>>>(Pfused, AN, attn_pb_b + l*768, a2bf);

    // ---- projections ----
    gbt<0><<<dim3(12,16,1),256,0,stream>>>(a2bf,768,0, wpool+OFF_Q,768,0,
        nullptr,768,0, qproj_bf, q_b + l*768, nullptr, nullptr, nullptr, 768, 1.f);
    gbt<0><<<dim3(36,16,1),256,0,stream>>>(a2bf,768,0, wpool+OFF_KVG,768,0,
        kvg,2304,0, kvg_bf, nullptr, nullptr, nullptr, nullptr, 768, 1.f);

    // ---- scores[h,x,y] = K·Q/48 + Zp_fp16 ----
    gbt<1><<<dim3(16,16,16),256,0,stream>>>(kvg_bf,144,147456, qproj_bf,48,49152,
        scores,1024,1048576, nullptr, nullptr, Zp2 + (i64)l*16777216, nullptr, nullptr,
        48, 1.f/48.f);

    // ---- softmax stats + V^T + fused MFMA A^T·V with gating ----
    rowstat<<<16384,256,0,stream>>>(scores, rstats);
    vtrans<<<dim3(16,16),256,0,stream>>>(kvg, Vt_h);
    av_gemm<<<dim3(1,16,16),256,0,stream>>>(scores, rstats, Vt_h, kvg, ogated_bf);

    // ---- gates: fused OUT|TRS gemm (N=1536) into gfused (scores region now dead) ----
    gbt<0><<<dim3(24,16,1),256,0,stream>>>(s_bf,384,0, wpool+OFF_OUT,384,0,
        gfused,1536,0, nullptr, gbias + l*1536, nullptr, nullptr, nullptr, 384, 1.f);

    // ---- AO gemm with fused attn gate ----
    gbt<3><<<dim3(12,16,1),256,0,stream>>>(ogated_bf,768,0, wpool+OFF_AO,768,0,
        attnmm,768,0, nullptr, nullptr, gfused, nullptr, nullptr, 768, 1.f);

    // ---- ConditionedTransitionBlock: fused TPB|TPNB gemm ----
    gbt<0><<<dim3(24,16,1),256,0,stream>>>(SNw2_bf+384,768,0, wpool+OFF_TPB,384,0,
        Pfused,1536,0, nullptr, nullptr, nullptr, nullptr, nullptr, 384, 1.f);
    adaln2<<<3072,256,0,stream>>>(Pfused, AN, tr_pb_b + l*768, a2bf);

    gbt<0><<<dim3(48,16,1),256,0,stream>>>(a2bf,768,0, wpool+OFF_TRA,768,0,
        hbuf,3072,0, nullptr, nullptr, nullptr, nullptr, nullptr, 768, 1.f);
    silu_mul_bf<<<6144,256,0,stream>>>(hbuf, bbuf_bf, 1572864);

    // ---- TRB gemm with fused final combine: a_cur = attnmm + sig(sgate*trb) ----
    gbt<4><<<dim3(12,16,1),256,0,stream>>>(bbuf_bf,1536,0, wpool+OFF_TRB,1536,0,
        a_cur,768,0, nullptr, nullptr, attnmm, gfused + 768,
        (l==1) ? (float*)d_out : nullptr, 1536, 1.f);
  }
}

// Round 5
// 865.326 us; speedup vs baseline: 1.6656x; 1.0282x over previous
//
#include <hip/hip_runtime.h>
#include <hip/hip_bf16.h>
#include <hip/hip_fp16.h>

typedef long long i64;
typedef unsigned short u16;
typedef __attribute__((ext_vector_type(8))) short short8;
typedef __attribute__((ext_vector_type(8))) _Float16 half8;
typedef __attribute__((ext_vector_type(4))) float f32x4;

__device__ __forceinline__ float sigf(float x){ return 1.f/(1.f + __expf(-x)); }
__device__ __forceinline__ u16 f2bu(float v){
  union{ __hip_bfloat16 h; u16 u; } cv; cv.h = __float2bfloat16(v); return cv.u;
}
__device__ __forceinline__ u16 f2hu(float v){
  union{ _Float16 h; u16 u; } cv; cv.h = (_Float16)v; return cv.u;
}
__device__ __forceinline__ float h2f(u16 u){
  union{ u16 u; _Float16 h; } cv; cv.u = u; return (float)cv.h;
}

// ---------------- f32 -> bf16 vectorized convert ----------------
__global__ void f2b(const float* __restrict__ in, u16* __restrict__ outp, long n){
  long i = ((long)blockIdx.x*256 + threadIdx.x)*4;
  if (i < n){
    float4 v = *(const float4*)(in + i);
    outp[i]   = f2bu(v.x); outp[i+1] = f2bu(v.y);
    outp[i+2] = f2bu(v.z); outp[i+3] = f2bu(v.w);
  }
}

// ---------------- per-layer weight pool convert (11 arrays, reordered pool) ----------------
// pool order: PB | PNB | Q | KVG | AO | OUT | TRS | TPB | TPNB | TRA | TRB
__global__ void f2b_wpool(const float* __restrict__ w0, const float* __restrict__ w1,
                          const float* __restrict__ w2, const float* __restrict__ w3,
                          const float* __restrict__ w4, const float* __restrict__ w5,
                          const float* __restrict__ w6, const float* __restrict__ w7,
                          const float* __restrict__ w8, const float* __restrict__ w9,
                          const float* __restrict__ w10, u16* __restrict__ pool){
  long i = ((long)blockIdx.x*256 + threadIdx.x)*4;
  if (i >= 8257536) return;
  const float* src; long rel;
  if      (i <  294912){ src=w0;  rel=i; }
  else if (i <  589824){ src=w1;  rel=i-294912; }
  else if (i < 1179648){ src=w2;  rel=i-589824; }
  else if (i < 2949120){ src=w3;  rel=i-1179648; }
  else if (i < 3538944){ src=w4;  rel=i-2949120; }
  else if (i < 3833856){ src=w5;  rel=i-3538944; }
  else if (i < 4128768){ src=w6;  rel=i-3833856; }
  else if (i < 4423680){ src=w7;  rel=i-4128768; }
  else if (i < 4718592){ src=w8;  rel=i-4423680; }
  else if (i < 7077888){ src=w9;  rel=i-4718592; }
  else                 { src=w10; rel=i-7077888; }
  float4 v = *(const float4*)(src + rel);
  pool[i]   = f2bu(v.x); pool[i+1] = f2bu(v.y);
  pool[i+2] = f2bu(v.z); pool[i+3] = f2bu(v.w);
}

// ---------------- LayerNorm over rows (no affine) ----------------
__global__ __launch_bounds__(256) void ln_rows(const float* __restrict__ x,
                                               float* __restrict__ y, int D){
  long base = (long)blockIdx.x * D;
  int t = threadIdx.x;
  float s = 0.f, ss = 0.f;
  for (int i = t; i < D; i += 256){ float v = x[base+i]; s += v; ss += v*v; }
  __shared__ float r0[256], r1[256];
  r0[t] = s; r1[t] = ss; __syncthreads();
  for (int off = 128; off > 0; off >>= 1){
    if (t < off){ r0[t] += r0[t+off]; r1[t] += r1[t+off]; }
    __syncthreads();
  }
  float mean = r0[0]/D;
  float var  = r1[0]/D - mean*mean;
  float rstd = rsqrtf(var + 1e-5f);
  for (int i = t; i < D; i += 256) y[base+i] = (x[base+i]-mean)*rstd;
}

// ---------------- SNw2[t][0:384]=SN0*w_at, [384:768]=SN0*w_tr ----------------
__global__ void scale2(const float* __restrict__ SN0, const float* __restrict__ w_at,
                       const float* __restrict__ w_tr, u16* __restrict__ y){
  long i = (long)blockIdx.x*256 + threadIdx.x;
  if (i < 786432){
    long tt = i/768, c = i%768;
    float v = (c < 384) ? SN0[tt*384+c]*w_at[c] : SN0[tt*384+c-384]*w_tr[c-384];
    y[i] = f2bu(v);
  }
}

// ---------------- a2_bf from fused P buffer [1024][1536]: sig((P1+b)*AN + P2) ----------------
__global__ void adaln2(const float* __restrict__ Pf, const float* __restrict__ AN,
                       const float* __restrict__ b, u16* __restrict__ outb){
  long i = (long)blockIdx.x*256 + threadIdx.x;
  if (i < 786432){
    long tt = i/768, c = i%768;
    float p1 = Pf[tt*1536 + c] + b[c];
    float p2 = Pf[tt*1536 + 768 + c];
    outb[i] = f2bu(sigf(p1*AN[i] + p2));
  }
}

// ---------------- combined gate biases: gbias[l][0:768]=out_b, [768:1536]=tr_s_b ----------------
__global__ void catbias(const float* __restrict__ ob, const float* __restrict__ tb,
                        float* __restrict__ g){
  int i = blockIdx.x*256 + threadIdx.x;
  if (i < 3072){
    int l = i/1536, c = i%1536;
    g[i] = (c < 768) ? ob[l*768+c] : tb[l*768+c-768];
  }
}

// ---------------- zprep: fold LN-affine into proj weights, emit fp16 ----------------
__global__ void zprep(const float* __restrict__ pw, const float* __restrict__ pb,
                      const float* __restrict__ bw, const float* __restrict__ bb,
                      u16* __restrict__ cwh, float* __restrict__ cb){
  int i = blockIdx.x*256 + threadIdx.x;
  if (i < 2048){
    int l = i/1024, c = i%64;
    cwh[i] = f2hu(pw[l*64+c]*bw[i]);
  } else if (i < 2080){
    int t = i - 2048;
    int l = t/16, mm = t%16;
    float acc = bb[l*16+mm];
    for (int c = 0; c < 64; c++) acc += pb[l*64+c]*bw[l*1024+mm*64+c];
    cb[t] = acc;
  }
}

// ---------------- zln_mfma: coalesced z load + 16-lane-group LN -> LDS fp16 -> MFMA ----------------
// Zp[l] flat (x,y,16h) fp16 — raw-reshape view as [h][x][y] matches torch.
__global__ __launch_bounds__(256) void zln_mfma(const float* __restrict__ z,
    const u16* __restrict__ Bw,   // fp16 [32][64], row = l*16+mm
    const float* __restrict__ cb, // f32 [32]
    u16* __restrict__ Zp){
  __shared__ __align__(16) u16 Asm[256*72];   // 36 KB; A tile, reused for output staging
  __shared__ __align__(16) u16 Bsm[32*72];    // 4.5 KB
  int t = threadIdx.x;
  i64 p0 = (i64)blockIdx.x*256;
  // stage B (32 rows x 64 fp16), 64 threads x 32B
  if (t < 64){
    int row = t >> 1, half = t & 1;
    const uint4* src = (const uint4*)(Bw + row*64 + half*32);
    uint4* dst = (uint4*)&Bsm[row*72 + half*32];
    dst[0]=src[0]; dst[1]=src[1]; dst[2]=src[2]; dst[3]=src[3];
  }
  // coalesced load + LN: 16 iterations; each iter 16 rows x 16 lanes x float4 (4KB contig)
  int sub = t & 15, rbase = t >> 4;
  const float* zb = z + p0*64;
#pragma unroll
  for (int it = 0; it < 16; it++){
    int row = it*16 + rbase;
    float4 v = *(const float4*)(zb + (i64)row*64 + sub*4);
    float s  = v.x+v.y+v.z+v.w;
    float ss = v.x*v.x+v.y*v.y+v.z*v.z+v.w*v.w;
#pragma unroll
    for (int mk = 1; mk < 16; mk <<= 1){
      s  += __shfl_xor(s,  mk);
      ss += __shfl_xor(ss, mk);
    }
    float mean = s*(1.f/64.f);
    float var  = ss*(1.f/64.f) - mean*mean;
    float r = rsqrtf(var + 1e-5f);
    unsigned int lo = (unsigned int)f2hu((v.x-mean)*r) | ((unsigned int)f2hu((v.y-mean)*r) << 16);
    unsigned int hi = (unsigned int)f2hu((v.z-mean)*r) | ((unsigned int)f2hu((v.w-mean)*r) << 16);
    *(uint2*)&Asm[row*72 + sub*4] = make_uint2(lo, hi);
  }
  __syncthreads();
  // MFMA: per wave M=64 (4 frags), N=32 (2 frags), K=64 (2 chunks)
  int lane = t & 63, wv = t >> 6, la = lane & 15, quad = lane >> 4;
  f32x4 acc[4][2] = {};
#pragma unroll
  for (int kc = 0; kc < 2; kc++){
    half8 af[4], bf[2];
#pragma unroll
    for (int i = 0; i < 4; i++)
      af[i] = *(const half8*)&Asm[(64*wv + 16*i + la)*72 + kc*32 + quad*8];
#pragma unroll
    for (int j = 0; j < 2; j++)
      bf[j] = *(const half8*)&Bsm[(16*j + la)*72 + kc*32 + quad*8];
#pragma unroll
    for (int i = 0; i < 4; i++)
#pragma unroll
      for (int j = 0; j < 2; j++)
        acc[i][j] = __builtin_amdgcn_mfma_f32_16x16x32_f16(af[i], bf[j], acc[i][j], 0,0,0);
  }
  __syncthreads();
  // stage results into Asm as [pos][32] fp16 (+bias)
#pragma unroll
  for (int i = 0; i < 4; i++)
#pragma unroll
   for (int j = 0; j < 2; j++)
#pragma unroll
    for (int rr = 0; rr < 4; rr++){
      int row = 64*wv + 16*i + quad*4 + rr;
      int gn = 16*j + la;
      Asm[row*72 + gn] = f2hu(acc[i][j][rr] + cb[gn]);
    }
  __syncthreads();
  // coalesced fp16 writes: layer0 = cols 0..15, layer1 = cols 16..31
  uint4* o0 = (uint4*)(Zp + (p0 + t)*16);
  uint4* o1 = (uint4*)(Zp + 16777216 + (p0 + t)*16);
  o0[0] = *(uint4*)&Asm[t*72];
  o0[1] = *(uint4*)&Asm[t*72 + 8];
  o1[0] = *(uint4*)&Asm[t*72 + 16];
  o1[1] = *(uint4*)&Asm[t*72 + 24];
}

// ---------------- per-row softmax stats: (max, 1/sum(exp)) ----------------
__global__ __launch_bounds__(256) void rowstat(const float* __restrict__ sc,
                                               float2* __restrict__ st){
  long base = (long)blockIdx.x * 1024;
  const float4* row = (const float4*)(sc + base);
  int t = threadIdx.x;
  float4 v = row[t];
  float mx = fmaxf(fmaxf(v.x,v.y), fmaxf(v.z,v.w));
  for (int off = 32; off > 0; off >>= 1) mx = fmaxf(mx, __shfl_down(mx, off));
  __shared__ float sm[4], ssum[4];
  int wv = t >> 6, ln = t & 63;
  if (ln == 0) sm[wv] = mx;
  __syncthreads();
  mx = fmaxf(fmaxf(sm[0],sm[1]), fmaxf(sm[2],sm[3]));
  float s = __expf(v.x-mx)+__expf(v.y-mx)+__expf(v.z-mx)+__expf(v.w-mx);
  for (int off = 32; off > 0; off >>= 1) s += __shfl_down(s, off);
  if (ln == 0) ssum[wv] = s;
  __syncthreads();
  if (t == 0) st[blockIdx.x] = make_float2(mx, 1.f/(ssum[0]+ssum[1]+ssum[2]+ssum[3]));
}

// ---------------- V transpose: kvg fp32 [h][x][144]+48 -> Vt fp16 [h][48][1024] ----------------
__global__ __launch_bounds__(256) void vtrans(const float* __restrict__ kvg,
                                              u16* __restrict__ vt){
  int h = blockIdx.x, x0 = blockIdx.y*64;
  __shared__ u16 tile[48][65];
  int t = threadIdx.x;
  for (int idx = t; idx < 64*48; idx += 256){
    int xx = idx/48, c = idx%48;
    tile[c][xx] = f2hu(kvg[(i64)h*147456 + (i64)(x0+xx)*144 + 48 + c]);
  }
  __syncthreads();
  for (int idx = t; idx < 48*64; idx += 256){
    int c = idx>>6, xx = idx&63;
    vt[(i64)h*49152 + (i64)c*1024 + x0 + xx] = tile[c][xx];
  }
}

// ---------------- MFMA fp16 A·V (software-pipelined): o = sig(g)*Σ_k P[k][m]·V[k][c] ----------------
__global__ __launch_bounds__(256) void av_gemm(
    const float* __restrict__ P,      // fp32 raw scores [h][1024 k][1024 m]
    const float2* __restrict__ st,    // [h*1024] (rowmax, 1/sum)
    const u16* __restrict__ Vt,      // fp16 [h][48][1024 k]
    const float* __restrict__ kvg,    // fp32, gate at +96, [h][m][144]
    u16* __restrict__ Ob)             // bf16 out [h][m][48]
{
  __shared__ __align__(16) u16 Asm[64*40];
  __shared__ __align__(16) u16 Bsm[64*40];
  int t = threadIdx.x;
  int h = blockIdx.z;
  int m0 = blockIdx.y*64;
  const float* Pp = P + (i64)h*1048576;
  const float2* stp = st + (i64)h*1024;
  const u16* Vp = Vt + (i64)h*49152;
  int lane = t & 63, wv = t >> 6;
  int la = lane & 15, quad = lane >> 4;
  int moff = (wv >> 1)*32, noff = (wv & 1)*32;
  int mcol = t & 63;
  int kr0  = (t >> 6)*2;
  int srow = t >> 2, skc = (t & 3)*8;
  f32x4 acc[2][2] = {{{0.f,0.f,0.f,0.f},{0.f,0.f,0.f,0.f}},
                     {{0.f,0.f,0.f,0.f},{0.f,0.f,0.f,0.f}}};
  float va[4], vb[4];
  float2 sa[4], sb[4];
  uint4 bv;
#pragma unroll
  for (int q = 0; q < 4; q++){
    int kk = kr0 + q*8;
    sa[q] = stp[kk]; sb[q] = stp[kk+1];
    va[q] = Pp[(i64)kk*1024 + m0 + mcol];
    vb[q] = Pp[(i64)(kk+1)*1024 + m0 + mcol];
  }
  bv = make_uint4(0,0,0,0);
  if (srow < 48) bv = *(const uint4*)(Vp + (i64)srow*1024 + skc);
  for (int it = 0; it < 32; it++){
#pragma unroll
    for (int q = 0; q < 4; q++){
      int kk = kr0 + q*8;
      unsigned int pa = f2hu(__expf(va[q] - sa[q].x) * sa[q].y);
      unsigned int pb = f2hu(__expf(vb[q] - sb[q].x) * sb[q].y);
      *(unsigned int*)&Asm[mcol*40 + kk] = pa | (pb << 16);
    }
    *(uint4*)&Bsm[srow*40 + skc] = bv;
    __syncthreads();
    if (it < 31){
      int k0 = (it+1)*32;
#pragma unroll
      for (int q = 0; q < 4; q++){
        int kk = kr0 + q*8;
        sa[q] = stp[k0+kk]; sb[q] = stp[k0+kk+1];
        va[q] = Pp[(i64)(k0+kk)*1024 + m0 + mcol];
        vb[q] = Pp[(i64)(k0+kk+1)*1024 + m0 + mcol];
      }
      bv = make_uint4(0,0,0,0);
      if (srow < 48) bv = *(const uint4*)(Vp + (i64)srow*1024 + k0 + skc);
    }
    half8 af0 = *(const half8*)&Asm[(moff      + la)*40 + quad*8];
    half8 af1 = *(const half8*)&Asm[(moff + 16 + la)*40 + quad*8];
    half8 bf0 = *(const half8*)&Bsm[(noff      + la)*40 + quad*8];
    half8 bf1 = *(const half8*)&Bsm[(noff + 16 + la)*40 + quad*8];
    acc[0][0] = __builtin_amdgcn_mfma_f32_16x16x32_f16(af0, bf0, acc[0][0], 0,0,0);
    acc[0][1] = __builtin_amdgcn_mfma_f32_16x16x32_f16(af0, bf1, acc[0][1], 0,0,0);
    acc[1][0] = __builtin_amdgcn_mfma_f32_16x16x32_f16(af1, bf0, acc[1][0], 0,0,0);
    acc[1][1] = __builtin_amdgcn_mfma_f32_16x16x32_f16(af1, bf1, acc[1][1], 0,0,0);
    __syncthreads();
  }
#pragma unroll
  for (int i = 0; i < 2; i++)
#pragma unroll
   for (int j = 0; j < 2; j++)
#pragma unroll
    for (int r = 0; r < 4; r++){
      int gm = m0 + moff + 16*i + quad*4 + r;
      int gn = noff + 16*j + la;
      if (gn < 48){
        float g = kvg[(i64)h*147456 + (i64)gm*144 + 96 + gn];
        float v = sigf(g) * acc[i][j][r];
        Ob[(i64)h*49152 + (i64)gm*48 + gn] = f2bu(v);
      }
    }
}

// ---------------- bb_bf = silu(h1)*h2 ----------------
__global__ void silu_mul_bf(const float* __restrict__ h, u16* __restrict__ bb, long n){
  long i = (long)blockIdx.x*256 + threadIdx.x;
  if (i < n){
    long tt = i/1536, c = i%1536;
    float h1 = h[tt*3072 + c], h2 = h[tt*3072 + 1536 + c];
    bb[i] = f2bu(h1*sigf(h1)*h2);
  }
}

// ---------------- bf16 MFMA GEMM (BK=64): C(M,N) = A(M,K)·B(N,K)^T, batched/strided ----------------
// EPI 0: r(+bias[n]) -> C (f32, optional) and/or Cbf
// EPI 1: C = alpha*r + fp16 X1[bz*sbC + idx]   (pair-bias add, no RMW)
// EPI 3: C = sigf(X1f[gm*1536+gn]) * r          (attn gate fused into AO)
// EPI 4: res = X1f[gm*768+gn] + sigf(X2f[gm*1536+gn]*r); C=res; C2?=res  (final combine)
template<int EPI>
__global__ __launch_bounds__(256) void gbt(
    const u16* __restrict__ A, i64 lda, i64 sbA,
    const u16* __restrict__ B, i64 ldb, i64 sbB,
    float* __restrict__ C, i64 ldc, i64 sbC,
    u16* __restrict__ Cbf,
    const float* __restrict__ bias,
    const void* __restrict__ X1, const void* __restrict__ X2,
    float* __restrict__ C2,
    int K, float alpha)
{
  __shared__ __align__(16) u16 Asm[64*72];
  __shared__ __align__(16) u16 Bsm[64*72];
  int t = threadIdx.x;
  int bz = blockIdx.z;
  int m0 = blockIdx.y*64, n0 = blockIdx.x*64;
  int srow = t >> 2, skc = (t & 3)*16;
  const u16* Ar = A + (i64)bz*sbA + (i64)(m0+srow)*lda;
  const u16* Br = B + (i64)bz*sbB + (i64)(n0+srow)*ldb;
  int lane = t & 63, wv = t >> 6;
  int la = lane & 15, quad = lane >> 4;
  int moff = (wv >> 1)*32, noff = (wv & 1)*32;
  f32x4 acc[2][2] = {{{0.f,0.f,0.f,0.f},{0.f,0.f,0.f,0.f}},
                     {{0.f,0.f,0.f,0.f},{0.f,0.f,0.f,0.f}}};
  for (int k0 = 0; k0 < K; k0 += 64){
    uint4 av0 = make_uint4(0,0,0,0), av1 = av0, bv0 = av0, bv1 = av0;
    if (k0 + skc < K){
      av0 = *(const uint4*)(Ar + k0 + skc);
      bv0 = *(const uint4*)(Br + k0 + skc);
    }
    if (k0 + skc + 8 < K){
      av1 = *(const uint4*)(Ar + k0 + skc + 8);
      bv1 = *(const uint4*)(Br + k0 + skc + 8);
    }
    *(uint4*)&Asm[srow*72 + skc]     = av0;
    *(uint4*)&Asm[srow*72 + skc + 8] = av1;
    *(uint4*)&Bsm[srow*72 + skc]     = bv0;
    *(uint4*)&Bsm[srow*72 + skc + 8] = bv1;
    __syncthreads();
#pragma unroll
    for (int kc = 0; kc < 2; kc++){
      short8 af0 = *(const short8*)&Asm[(moff      + la)*72 + kc*32 + quad*8];
      short8 af1 = *(const short8*)&Asm[(moff + 16 + la)*72 + kc*32 + quad*8];
      short8 bf0 = *(const short8*)&Bsm[(noff      + la)*72 + kc*32 + quad*8];
      short8 bf1 = *(const short8*)&Bsm[(noff + 16 + la)*72 + kc*32 + quad*8];
      acc[0][0] = __builtin_amdgcn_mfma_f32_16x16x32_bf16(af0, bf0, acc[0][0], 0,0,0);
      acc[0][1] = __builtin_amdgcn_mfma_f32_16x16x32_bf16(af0, bf1, acc[0][1], 0,0,0);
      acc[1][0] = __builtin_amdgcn_mfma_f32_16x16x32_bf16(af1, bf0, acc[1][0], 0,0,0);
      acc[1][1] = __builtin_amdgcn_mfma_f32_16x16x32_bf16(af1, bf1, acc[1][1], 0,0,0);
    }
    __syncthreads();
  }
  float* Cb = C ? C + (i64)bz*sbC : nullptr;
  u16* Cb2 = Cbf ? Cbf + (i64)bz*sbC : nullptr;
  const u16* zp = (EPI == 1) ? (const u16*)X1 + (i64)bz*sbC : nullptr;
#pragma unroll
  for (int i = 0; i < 2; i++)
#pragma unroll
   for (int j = 0; j < 2; j++)
#pragma unroll
    for (int r = 0; r < 4; r++){
      int gm = m0 + moff + 16*i + quad*4 + r;
      int gn = n0 + noff + 16*j + la;
      i64 idx = (i64)gm*ldc + gn;
      float v = acc[i][j][r];
      if (EPI == 1){
        Cb[idx] = alpha*v + h2f(zp[idx]);
      } else if (EPI == 3){
        const float* g = (const float*)X1;
        Cb[idx] = sigf(g[(i64)gm*1536 + gn]) * v;
      } else if (EPI == 4){
        const float* am = (const float*)X1;
        const float* sg = (const float*)X2;
        float res = am[(i64)gm*768 + gn] + sigf(sg[(i64)gm*1536 + gn] * v);
        Cb[idx] = res;
        if (C2) C2[idx] = res;
      } else {
        if (bias) v += bias[gn];
        if (Cb)  Cb[idx]  = v;
        if (Cb2) Cb2[idx] = f2bu(v);
      }
    }
}

extern "C" void kernel_launch(void* const* d_in, const int* in_sizes, int n_in,
                              void* d_out, int out_size, void* d_ws, size_t ws_size,
                              hipStream_t stream){
  const float* a_in   = (const float*)d_in[0];
  const float* s_in   = (const float*)d_in[1];
  const float* z_in   = (const float*)d_in[2];
  const float* attn_sn_w = (const float*)d_in[3];
  const float* attn_pb_w = (const float*)d_in[4];
  const float* attn_pb_b = (const float*)d_in[5];
  const float* attn_pnb_w= (const float*)d_in[6];
  const float* pair_w = (const float*)d_in[7];
  const float* pair_b = (const float*)d_in[8];
  const float* q_w    = (const float*)d_in[9];
  const float* q_b    = (const float*)d_in[10];
  const float* kvg_w  = (const float*)d_in[11];
  const float* bias_w = (const float*)d_in[12];
  const float* bias_b = (const float*)d_in[13];
  const float* ao_w   = (const float*)d_in[14];
  const float* out_w  = (const float*)d_in[15];
  const float* out_b  = (const float*)d_in[16];
  const float* tr_sn_w= (const float*)d_in[17];
  const float* tr_pb_w= (const float*)d_in[18];
  const float* tr_pb_b= (const float*)d_in[19];
  const float* tr_pnb_w=(const float*)d_in[20];
  const float* tr_a_w = (const float*)d_in[21];
  const float* tr_s_w = (const float*)d_in[22];
  const float* tr_s_b = (const float*)d_in[23];
  const float* tr_b_w = (const float*)d_in[24];

  // -------- workspace layout (f32 elems from base) --------
  float* ws      = (float*)d_ws;
  float* scores  = ws;                     // 16777216 f32 [h][x][y]; region reused post-attn
  float* hbuf    = scores;                 // + 0       : 3145728  (TRA out)
  float* gfused  = scores + 3145728;       // + 3145728 : 1572864  ([1024][1536] gate|sgate)
  float* attnmm  = scores + 4718592;       // + 4718592 : 786432   (gated AO out)
  float* a_cur   = ws + 16777216;          // 786432
  float* AN      = a_cur + 786432;         // 786432
  float* SN0     = AN + 786432;            // 393216
  float* Pfused  = SN0 + 393216;           // 1572864 ([1024][1536])
  float* kvg     = Pfused + 1572864;       // 2359296
  float* vaux    = kvg + 2359296;          // 786432 (Vt fp16 + rowstats)
  float* gbias   = vaux + 786432;          // 3072
  float* zcw     = gbias + 3072;           // 2048 f32 region (first 1024 used as u16[2048])
  float* zcb     = zcw + 2048;             // 32 (+pad)
  u16* wpool     = (u16*)(zcb + 64);       // 8257536
  u16* SNw2_bf   = wpool + 8257536;        // 786432 ([1024][768], attn|tr halves)
  u16* s_bf      = SNw2_bf + 786432;       // 393216
  u16* a2bf      = s_bf + 393216;          // 786432
  u16* qproj_bf  = a2bf + 786432;          // 786432
  u16* kvg_bf    = qproj_bf + 786432;      // 2359296
  u16* ogated_bf = kvg_bf + 2359296;       // 786432
  u16* bbuf_bf   = ogated_bf + 786432;     // 1572864
  u16* Zp2       = bbuf_bf + 1572864;      // 33554432 (fp16 pair bias, both layers)

  u16*    Vt_h   = (u16*)vaux;             // 786432 u16
  float2* rstats = (float2*)(vaux + 393216);
  u16*    zcwh   = (u16*)zcw;              // fp16 [32][64]

  // pool offsets (bf16 elems) — reordered: PB|PNB|Q|KVG|AO|OUT|TRS|TPB|TPNB|TRA|TRB
  const i64 OFF_PB=0, OFF_Q=589824, OFF_KVG=1179648, OFF_AO=2949120,
            OFF_OUT=3538944, OFF_TPB=4128768, OFF_TRA=4718592, OFF_TRB=7077888;

  f2b<<<384,256,0,stream>>>(s_in, s_bf, 393216);
  ln_rows<<<1024,256,0,stream>>>(s_in, SN0, 384);   // LN(s), layer-independent
  catbias<<<12,256,0,stream>>>(out_b, tr_s_b, gbias);
  zprep<<<9,256,0,stream>>>(pair_w, pair_b, bias_w, bias_b, zcwh, zcb);
  zln_mfma<<<4096,256,0,stream>>>(z_in, zcwh, zcb, Zp2);  // one z read, both layers, fp16

  for (int l = 0; l < 2; l++){
    f2b_wpool<<<8064,256,0,stream>>>(
        attn_pb_w + (i64)l*294912, attn_pnb_w + (i64)l*294912,
        q_w + (i64)l*589824, kvg_w + (i64)l*1769472, ao_w + (i64)l*589824,
        out_w + (i64)l*294912, tr_s_w + (i64)l*294912,
        tr_pb_w + (i64)l*294912, tr_pnb_w + (i64)l*294912,
        tr_a_w + (i64)l*2359296, tr_b_w + (i64)l*1179648, wpool);

    ln_rows<<<1024,256,0,stream>>>(l == 0 ? a_in : a_cur, AN, 768);
    scale2<<<3072,256,0,stream>>>(SN0, attn_sn_w + l*384, tr_sn_w + l*384, SNw2_bf);

    // ---- AttentionPairBias adaln: fused PB|PNB gemm (N=1536) ----
    gbt<0><<<dim3(24,16,1),256,0,stream>>>(SNw2_bf,768,0, wpool+OFF_PB,384,0,
        Pfused,1536,0, nullptr, nullptr, nullptr, nullptr, nullptr, 384, 1.f);
    adaln2<<<3072,256,0,stream>>>(Pfused, AN, attn_pb_b + l*768, a2bf);

    // ---- projections ----
    gbt<0><<<dim3(12,16,1),256,0,stream>>>(a2bf,768,0, wpool+OFF_Q,768,0,
        nullptr,768,0, qproj_bf, q_b + l*768, nullptr, nullptr, nullptr, 768, 1.f);
    gbt<0><<<dim3(36,16,1),256,0,stream>>>(a2bf,768,0, wpool+OFF_KVG,768,0,
        kvg,2304,0, kvg_bf, nullptr, nullptr, nullptr, nullptr, 768, 1.f);

    // ---- scores[h,x,y] = K·Q/48 + Zp_fp16 ----
    gbt<1><<<dim3(16,16,16),256,0,stream>>>(kvg_bf,144,147456, qproj_bf,48,49152,
        scores,1024,1048576, nullptr, nullptr, Zp2 + (i64)l*16777216, nullptr, nullptr,
        48, 1.f/48.f);

    // ---- softmax stats + V^T + fused MFMA A^T·V with gating ----
    rowstat<<<16384,256,0,stream>>>(scores, rstats);
    vtrans<<<dim3(16,16),256,0,stream>>>(kvg, Vt_h);
    av_gemm<<<dim3(1,16,16),256,0,stream>>>(scores, rstats, Vt_h, kvg, ogated_bf);

    // ---- gates: fused OUT|TRS gemm (N=1536) into gfused (scores region now dead) ----
    gbt<0><<<dim3(24,16,1),256,0,stream>>>(s_bf,384,0, wpool+OFF_OUT,384,0,
        gfused,1536,0, nullptr, gbias + l*1536, nullptr, nullptr, nullptr, 384, 1.f);

    // ---- AO gemm with fused attn gate ----
    gbt<3><<<dim3(12,16,1),256,0,stream>>>(ogated_bf,768,0, wpool+OFF_AO,768,0,
        attnmm,768,0, nullptr, nullptr, gfused, nullptr, nullptr, 768, 1.f);

    // ---- ConditionedTransitionBlock: fused TPB|TPNB gemm ----
    gbt<0><<<dim3(24,16,1),256,0,stream>>>(SNw2_bf+384,768,0, wpool+OFF_TPB,384,0,
        Pfused,1536,0, nullptr, nullptr, nullptr, nullptr, nullptr, 384, 1.f);
    adaln2<<<3072,256,0,stream>>>(Pfused, AN, tr_pb_b + l*768, a2bf);

    gbt<0><<<dim3(48,16,1),256,0,stream>>>(a2bf,768,0, wpool+OFF_TRA,768,0,
        hbuf,3072,0, nullptr, nullptr, nullptr, nullptr, nullptr, 768, 1.f);
    silu_mul_bf<<<6144,256,0,stream>>>(hbuf, bbuf_bf, 1572864);

    // ---- TRB gemm with fused final combine: a_cur = attnmm + sig(sgate*trb) ----
    gbt<4><<<dim3(12,16,1),256,0,stream>>>(bbuf_bf,1536,0, wpool+OFF_TRB,1536,0,
        a_cur,768,0, nullptr, nullptr, attnmm, gfused + 768,
        (l==1) ? (float*)d_out : nullptr, 1536, 1.f);
  }
}

// Round 6
// 800.320 us; speedup vs baseline: 1.8009x; 1.0812x over previous
//
#include <hip/hip_runtime.h>
#include <hip/hip_bf16.h>
#include <hip/hip_fp16.h>

typedef long long i64;
typedef unsigned short u16;
typedef __attribute__((ext_vector_type(8))) short short8;
typedef __attribute__((ext_vector_type(8))) _Float16 half8;
typedef __attribute__((ext_vector_type(4))) float f32x4;

#define POOLSZ 8257536

__device__ __forceinline__ float sigf(float x){ return 1.f/(1.f + __expf(-x)); }
__device__ __forceinline__ u16 f2bu(float v){
  union{ __hip_bfloat16 h; u16 u; } cv; cv.h = __float2bfloat16(v); return cv.u;
}
__device__ __forceinline__ u16 f2hu(float v){
  union{ _Float16 h; u16 u; } cv; cv.h = (_Float16)v; return cv.u;
}
__device__ __forceinline__ float h2f(u16 u){
  union{ u16 u; _Float16 h; } cv; cv.u = u; return (float)cv.h;
}

// ---------------- f32 -> bf16 vectorized convert ----------------
__global__ void f2b(const float* __restrict__ in, u16* __restrict__ outp, long n){
  long i = ((long)blockIdx.x*256 + threadIdx.x)*4;
  if (i < n){
    float4 v = *(const float4*)(in + i);
    outp[i]   = f2bu(v.x); outp[i+1] = f2bu(v.y);
    outp[i+2] = f2bu(v.z); outp[i+3] = f2bu(v.w);
  }
}

// ---------------- weight pool convert, BOTH layers ----------------
// pool order per layer: PB | PNB | Q | KVG | AO | OUT | TRS | TPB | TPNB | TRA | TRB
__global__ void f2b_wpool(const float* __restrict__ w0, const float* __restrict__ w1,
                          const float* __restrict__ w2, const float* __restrict__ w3,
                          const float* __restrict__ w4, const float* __restrict__ w5,
                          const float* __restrict__ w6, const float* __restrict__ w7,
                          const float* __restrict__ w8, const float* __restrict__ w9,
                          const float* __restrict__ w10, u16* __restrict__ pool){
  long i = ((long)blockIdx.x*256 + threadIdx.x)*4;
  if (i >= 2L*POOLSZ) return;
  long l = i / POOLSZ;
  long j = i - l*POOLSZ;
  const float* src; long rel, ls;
  if      (j <  294912){ src=w0;  rel=j;          ls=294912; }
  else if (j <  589824){ src=w1;  rel=j-294912;   ls=294912; }
  else if (j < 1179648){ src=w2;  rel=j-589824;   ls=589824; }
  else if (j < 2949120){ src=w3;  rel=j-1179648;  ls=1769472; }
  else if (j < 3538944){ src=w4;  rel=j-2949120;  ls=589824; }
  else if (j < 3833856){ src=w5;  rel=j-3538944;  ls=294912; }
  else if (j < 4128768){ src=w6;  rel=j-3833856;  ls=294912; }
  else if (j < 4423680){ src=w7;  rel=j-4128768;  ls=294912; }
  else if (j < 4718592){ src=w8;  rel=j-4423680;  ls=294912; }
  else if (j < 7077888){ src=w9;  rel=j-4718592;  ls=2359296; }
  else                 { src=w10; rel=j-7077888;  ls=1179648; }
  float4 v = *(const float4*)(src + l*ls + rel);
  pool[i]   = f2bu(v.x); pool[i+1] = f2bu(v.y);
  pool[i+2] = f2bu(v.z); pool[i+3] = f2bu(v.w);
}

// ---------------- LayerNorm over rows (no affine) ----------------
__global__ __launch_bounds__(256) void ln_rows(const float* __restrict__ x,
                                               float* __restrict__ y, int D){
  long base = (long)blockIdx.x * D;
  int t = threadIdx.x;
  float s = 0.f, ss = 0.f;
  for (int i = t; i < D; i += 256){ float v = x[base+i]; s += v; ss += v*v; }
  __shared__ float r0[256], r1[256];
  r0[t] = s; r1[t] = ss; __syncthreads();
  for (int off = 128; off > 0; off >>= 1){
    if (t < off){ r0[t] += r0[t+off]; r1[t] += r1[t+off]; }
    __syncthreads();
  }
  float mean = r0[0]/D;
  float var  = r1[0]/D - mean*mean;
  float rstd = rsqrtf(var + 1e-5f);
  for (int i = t; i < D; i += 256) y[base+i] = (x[base+i]-mean)*rstd;
}

// ---------------- SNw2[l][t][0:384]=SN0*at_w[l], [384:768]=SN0*tr_w[l], both layers ----------------
__global__ void scale2(const float* __restrict__ SN0, const float* __restrict__ at_w,
                       const float* __restrict__ tr_w, u16* __restrict__ y){
  long i = (long)blockIdx.x*256 + threadIdx.x;
  if (i < 1572864){
    long l = i / 786432, j = i - l*786432;
    long tt = j/768, c = j%768;
    float v = (c < 384) ? SN0[tt*384+c]*at_w[l*384+c] : SN0[tt*384+c-384]*tr_w[l*384+c-384];
    y[i] = f2bu(v);
  }
}

// ---------------- a2_bf from fused P buffer [1024][1536]: sig((P1+b)*AN + P2) ----------------
__global__ void adaln2(const float* __restrict__ Pf, const float* __restrict__ AN,
                       const float* __restrict__ b, u16* __restrict__ outb){
  long i = (long)blockIdx.x*256 + threadIdx.x;
  if (i < 786432){
    long tt = i/768, c = i%768;
    float p1 = Pf[tt*1536 + c] + b[c];
    float p2 = Pf[tt*1536 + 768 + c];
    outb[i] = f2bu(sigf(p1*AN[i] + p2));
  }
}

// ---------------- prep_small: gate biases + zprep fold ----------------
__global__ void prep_small(const float* __restrict__ ob, const float* __restrict__ tb,
                           float* __restrict__ g,
                           const float* __restrict__ pw, const float* __restrict__ pb,
                           const float* __restrict__ bw, const float* __restrict__ bb,
                           u16* __restrict__ cwh, float* __restrict__ cb){
  int i = blockIdx.x*256 + threadIdx.x;
  if (i < 3072){
    int l = i/1536, c = i%1536;
    g[i] = (c < 768) ? ob[l*768+c] : tb[l*768+c-768];
  }
  int j = i - 3072;
  if (j >= 0 && j < 2048){
    int l = j/1024, c = j%64;
    cwh[j] = f2hu(pw[l*64+c]*bw[j]);
  } else if (j >= 2048 && j < 2080){
    int t2 = j - 2048;
    int l = t2/16, mm = t2%16;
    float acc = bb[l*16+mm];
    for (int c = 0; c < 64; c++) acc += pb[l*64+c]*bw[l*1024+mm*64+c];
    cb[t2] = acc;
  }
}

// ---------------- zln_mfma: coalesced z load + 16-lane-group LN -> LDS fp16 -> MFMA ----------------
__global__ __launch_bounds__(256) void zln_mfma(const float* __restrict__ z,
    const u16* __restrict__ Bw, const float* __restrict__ cb, u16* __restrict__ Zp){
  __shared__ __align__(16) u16 Asm[256*72];
  __shared__ __align__(16) u16 Bsm[32*72];
  int t = threadIdx.x;
  i64 p0 = (i64)blockIdx.x*256;
  if (t < 64){
    int row = t >> 1, half = t & 1;
    const uint4* src = (const uint4*)(Bw + row*64 + half*32);
    uint4* dst = (uint4*)&Bsm[row*72 + half*32];
    dst[0]=src[0]; dst[1]=src[1]; dst[2]=src[2]; dst[3]=src[3];
  }
  int sub = t & 15, rbase = t >> 4;
  const float* zb = z + p0*64;
#pragma unroll
  for (int it = 0; it < 16; it++){
    int row = it*16 + rbase;
    float4 v = *(const float4*)(zb + (i64)row*64 + sub*4);
    float s  = v.x+v.y+v.z+v.w;
    float ss = v.x*v.x+v.y*v.y+v.z*v.z+v.w*v.w;
#pragma unroll
    for (int mk = 1; mk < 16; mk <<= 1){
      s  += __shfl_xor(s,  mk);
      ss += __shfl_xor(ss, mk);
    }
    float mean = s*(1.f/64.f);
    float var  = ss*(1.f/64.f) - mean*mean;
    float r = rsqrtf(var + 1e-5f);
    unsigned int lo = (unsigned int)f2hu((v.x-mean)*r) | ((unsigned int)f2hu((v.y-mean)*r) << 16);
    unsigned int hi = (unsigned int)f2hu((v.z-mean)*r) | ((unsigned int)f2hu((v.w-mean)*r) << 16);
    *(uint2*)&Asm[row*72 + sub*4] = make_uint2(lo, hi);
  }
  __syncthreads();
  int lane = t & 63, wv = t >> 6, la = lane & 15, quad = lane >> 4;
  f32x4 acc[4][2] = {};
#pragma unroll
  for (int kc = 0; kc < 2; kc++){
    half8 af[4], bf[2];
#pragma unroll
    for (int i = 0; i < 4; i++)
      af[i] = *(const half8*)&Asm[(64*wv + 16*i + la)*72 + kc*32 + quad*8];
#pragma unroll
    for (int j = 0; j < 2; j++)
      bf[j] = *(const half8*)&Bsm[(16*j + la)*72 + kc*32 + quad*8];
#pragma unroll
    for (int i = 0; i < 4; i++)
#pragma unroll
      for (int j = 0; j < 2; j++)
        acc[i][j] = __builtin_amdgcn_mfma_f32_16x16x32_f16(af[i], bf[j], acc[i][j], 0,0,0);
  }
  __syncthreads();
#pragma unroll
  for (int i = 0; i < 4; i++)
#pragma unroll
   for (int j = 0; j < 2; j++)
#pragma unroll
    for (int rr = 0; rr < 4; rr++){
      int row = 64*wv + 16*i + quad*4 + rr;
      int gn = 16*j + la;
      Asm[row*72 + gn] = f2hu(acc[i][j][rr] + cb[gn]);
    }
  __syncthreads();
  uint4* o0 = (uint4*)(Zp + (p0 + t)*16);
  uint4* o1 = (uint4*)(Zp + 16777216 + (p0 + t)*16);
  o0[0] = *(uint4*)&Asm[t*72];
  o0[1] = *(uint4*)&Asm[t*72 + 8];
  o1[0] = *(uint4*)&Asm[t*72 + 16];
  o1[1] = *(uint4*)&Asm[t*72 + 24];
}

// ---------------- merge per-block stats: rstats = (gmax, 1/total) ----------------
__global__ __launch_bounds__(256) void stat_merge(const float2* __restrict__ pt,
                                                  float2* __restrict__ st){
  int i = blockIdx.x*256 + threadIdx.x;   // h*1024 + k
  int h = i >> 10, k = i & 1023;
  const float2* p = pt + (i64)h*16384 + k;
  float mx[16], sm[16];
  float m = -3e38f;
#pragma unroll
  for (int nb = 0; nb < 16; nb++){
    float2 v = p[(i64)nb*1024];
    mx[nb] = v.x; sm[nb] = v.y;
    m = fmaxf(m, v.x);
  }
  float s = 0.f;
#pragma unroll
  for (int nb = 0; nb < 16; nb++) s += sm[nb]*__expf(mx[nb]-m);
  st[i] = make_float2(m, 1.f/s);
}

// ---------------- V transpose: kvg fp32 [h][x][144]+48 -> Vt fp16 [h][48][1024] ----------------
__global__ __launch_bounds__(256) void vtrans(const float* __restrict__ kvg,
                                              u16* __restrict__ vt){
  int h = blockIdx.x, x0 = blockIdx.y*64;
  __shared__ u16 tile[48][65];
  int t = threadIdx.x;
  for (int idx = t; idx < 64*48; idx += 256){
    int xx = idx/48, c = idx%48;
    tile[c][xx] = f2hu(kvg[(i64)h*147456 + (i64)(x0+xx)*144 + 48 + c]);
  }
  __syncthreads();
  for (int idx = t; idx < 48*64; idx += 256){
    int c = idx>>6, xx = idx&63;
    vt[(i64)h*49152 + (i64)c*1024 + x0 + xx] = tile[c][xx];
  }
}

// ---------------- MFMA fp16 A·V (software-pipelined): o = sig(g)*Σ_k P[k][m]·V[k][c] ----------------
__global__ __launch_bounds__(256) void av_gemm(
    const float* __restrict__ P, const float2* __restrict__ st,
    const u16* __restrict__ Vt, const float* __restrict__ kvg,
    u16* __restrict__ Ob)
{
  __shared__ __align__(16) u16 Asm[64*40];
  __shared__ __align__(16) u16 Bsm[64*40];
  int t = threadIdx.x;
  int h = blockIdx.z;
  int m0 = blockIdx.y*64;
  const float* Pp = P + (i64)h*1048576;
  const float2* stp = st + (i64)h*1024;
  const u16* Vp = Vt + (i64)h*49152;
  int lane = t & 63, wv = t >> 6;
  int la = lane & 15, quad = lane >> 4;
  int moff = (wv >> 1)*32, noff = (wv & 1)*32;
  int mcol = t & 63;
  int kr0  = (t >> 6)*2;
  int srow = t >> 2, skc = (t & 3)*8;
  f32x4 acc[2][2] = {{{0.f,0.f,0.f,0.f},{0.f,0.f,0.f,0.f}},
                     {{0.f,0.f,0.f,0.f},{0.f,0.f,0.f,0.f}}};
  float va[4], vb[4];
  float2 sa[4], sb[4];
  uint4 bv;
#pragma unroll
  for (int q = 0; q < 4; q++){
    int kk = kr0 + q*8;
    sa[q] = stp[kk]; sb[q] = stp[kk+1];
    va[q] = Pp[(i64)kk*1024 + m0 + mcol];
    vb[q] = Pp[(i64)(kk+1)*1024 + m0 + mcol];
  }
  bv = make_uint4(0,0,0,0);
  if (srow < 48) bv = *(const uint4*)(Vp + (i64)srow*1024 + skc);
  for (int it = 0; it < 32; it++){
#pragma unroll
    for (int q = 0; q < 4; q++){
      int kk = kr0 + q*8;
      unsigned int pa = f2hu(__expf(va[q] - sa[q].x) * sa[q].y);
      unsigned int pb = f2hu(__expf(vb[q] - sb[q].x) * sb[q].y);
      *(unsigned int*)&Asm[mcol*40 + kk] = pa | (pb << 16);
    }
    *(uint4*)&Bsm[srow*40 + skc] = bv;
    __syncthreads();
    if (it < 31){
      int k0 = (it+1)*32;
#pragma unroll
      for (int q = 0; q < 4; q++){
        int kk = kr0 + q*8;
        sa[q] = stp[k0+kk]; sb[q] = stp[k0+kk+1];
        va[q] = Pp[(i64)(k0+kk)*1024 + m0 + mcol];
        vb[q] = Pp[(i64)(k0+kk+1)*1024 + m0 + mcol];
      }
      bv = make_uint4(0,0,0,0);
      if (srow < 48) bv = *(const uint4*)(Vp + (i64)srow*1024 + k0 + skc);
    }
    half8 af0 = *(const half8*)&Asm[(moff      + la)*40 + quad*8];
    half8 af1 = *(const half8*)&Asm[(moff + 16 + la)*40 + quad*8];
    half8 bf0 = *(const half8*)&Bsm[(noff      + la)*40 + quad*8];
    half8 bf1 = *(const half8*)&Bsm[(noff + 16 + la)*40 + quad*8];
    acc[0][0] = __builtin_amdgcn_mfma_f32_16x16x32_f16(af0, bf0, acc[0][0], 0,0,0);
    acc[0][1] = __builtin_amdgcn_mfma_f32_16x16x32_f16(af0, bf1, acc[0][1], 0,0,0);
    acc[1][0] = __builtin_amdgcn_mfma_f32_16x16x32_f16(af1, bf0, acc[1][0], 0,0,0);
    acc[1][1] = __builtin_amdgcn_mfma_f32_16x16x32_f16(af1, bf1, acc[1][1], 0,0,0);
    __syncthreads();
  }
#pragma unroll
  for (int i = 0; i < 2; i++)
#pragma unroll
   for (int j = 0; j < 2; j++)
#pragma unroll
    for (int r = 0; r < 4; r++){
      int gm = m0 + moff + 16*i + quad*4 + r;
      int gn = noff + 16*j + la;
      if (gn < 48){
        float g = kvg[(i64)h*147456 + (i64)gm*144 + 96 + gn];
        float v = sigf(g) * acc[i][j][r];
        Ob[(i64)h*49152 + (i64)gm*48 + gn] = f2bu(v);
      }
    }
}

// ---------------- bb_bf = silu(h1)*h2 ----------------
__global__ void silu_mul_bf(const float* __restrict__ h, u16* __restrict__ bb, long n){
  long i = (long)blockIdx.x*256 + threadIdx.x;
  if (i < n){
    long tt = i/1536, c = i%1536;
    float h1 = h[tt*3072 + c], h2 = h[tt*3072 + 1536 + c];
    bb[i] = f2bu(h1*sigf(h1)*h2);
  }
}

// ---------------- bf16 MFMA GEMM (BK=64): C(M,N) = A(M,K)·B(N,K)^T, batched/strided ----------------
// EPI 0: r(+bias[bz*sbBias+n]) -> C and/or Cbf
// EPI 1: C = alpha*r + fp16 X1; per-row (max,sumexp) partials -> C2 (float2)
// EPI 3: C = sigf(X1f[gm*1536+gn]) * r
// EPI 4: res = X1f[gm*768+gn] + sigf(X2f[gm*1536+gn]*r); C=res; C2?=res
// EPI 5: gn<768 -> qproj_bf(C2)+bias; else kvg(C)/kvg_bf(Cbf)
template<int EPI>
__global__ __launch_bounds__(256) void gbt(
    const u16* __restrict__ A, i64 lda, i64 sbA,
    const u16* __restrict__ B, i64 ldb, i64 sbB,
    float* __restrict__ C, i64 ldc, i64 sbC,
    u16* __restrict__ Cbf,
    const float* __restrict__ bias, i64 sbBias,
    const void* __restrict__ X1, const void* __restrict__ X2,
    float* __restrict__ C2,
    int K, float alpha)
{
  __shared__ __align__(16) u16 Asm[64*72];
  __shared__ __align__(16) u16 Bsm[64*72];
  __shared__ float2 pst[2][64];
  int t = threadIdx.x;
  int bz = blockIdx.z;
  int m0 = blockIdx.y*64, n0 = blockIdx.x*64;
  int srow = t >> 2, skc = (t & 3)*16;
  const u16* Ar = A + (i64)bz*sbA + (i64)(m0+srow)*lda;
  const u16* Br = B + (i64)bz*sbB + (i64)(n0+srow)*ldb;
  int lane = t & 63, wv = t >> 6;
  int la = lane & 15, quad = lane >> 4;
  int moff = (wv >> 1)*32, noff = (wv & 1)*32;
  f32x4 acc[2][2] = {{{0.f,0.f,0.f,0.f},{0.f,0.f,0.f,0.f}},
                     {{0.f,0.f,0.f,0.f},{0.f,0.f,0.f,0.f}}};
  for (int k0 = 0; k0 < K; k0 += 64){
    uint4 av0 = make_uint4(0,0,0,0), av1 = av0, bv0 = av0, bv1 = av0;
    if (k0 + skc < K){
      av0 = *(const uint4*)(Ar + k0 + skc);
      bv0 = *(const uint4*)(Br + k0 + skc);
    }
    if (k0 + skc + 8 < K){
      av1 = *(const uint4*)(Ar + k0 + skc + 8);
      bv1 = *(const uint4*)(Br + k0 + skc + 8);
    }
    *(uint4*)&Asm[srow*72 + skc]     = av0;
    *(uint4*)&Asm[srow*72 + skc + 8] = av1;
    *(uint4*)&Bsm[srow*72 + skc]     = bv0;
    *(uint4*)&Bsm[srow*72 + skc + 8] = bv1;
    __syncthreads();
#pragma unroll
    for (int kc = 0; kc < 2; kc++){
      short8 af0 = *(const short8*)&Asm[(moff      + la)*72 + kc*32 + quad*8];
      short8 af1 = *(const short8*)&Asm[(moff + 16 + la)*72 + kc*32 + quad*8];
      short8 bf0 = *(const short8*)&Bsm[(noff      + la)*72 + kc*32 + quad*8];
      short8 bf1 = *(const short8*)&Bsm[(noff + 16 + la)*72 + kc*32 + quad*8];
      acc[0][0] = __builtin_amdgcn_mfma_f32_16x16x32_bf16(af0, bf0, acc[0][0], 0,0,0);
      acc[0][1] = __builtin_amdgcn_mfma_f32_16x16x32_bf16(af0, bf1, acc[0][1], 0,0,0);
      acc[1][0] = __builtin_amdgcn_mfma_f32_16x16x32_bf16(af1, bf0, acc[1][0], 0,0,0);
      acc[1][1] = __builtin_amdgcn_mfma_f32_16x16x32_bf16(af1, bf1, acc[1][1], 0,0,0);
    }
    __syncthreads();
  }
  float* Cb = C ? C + (i64)bz*sbC : nullptr;
  u16* Cb2 = Cbf ? Cbf + (i64)bz*sbC : nullptr;
  if (EPI == 1){
    const u16* zp = (const u16*)X1 + (i64)bz*sbC;
    float vv[2][2][4], rmax[2][4], rsum[2][4];
#pragma unroll
    for (int i = 0; i < 2; i++)
#pragma unroll
     for (int r = 0; r < 4; r++){ rmax[i][r] = -3e38f; rsum[i][r] = 0.f; }
#pragma unroll
    for (int i = 0; i < 2; i++)
#pragma unroll
     for (int j = 0; j < 2; j++)
#pragma unroll
      for (int r = 0; r < 4; r++){
        int gm = m0 + moff + 16*i + quad*4 + r;
        int gn = n0 + noff + 16*j + la;
        i64 idx = (i64)gm*ldc + gn;
        float v = alpha*acc[i][j][r] + h2f(zp[idx]);
        Cb[idx] = v;
        vv[i][j][r] = v;
        rmax[i][r] = fmaxf(rmax[i][r], v);
      }
#pragma unroll
    for (int mk = 1; mk < 16; mk <<= 1)
#pragma unroll
      for (int i = 0; i < 2; i++)
#pragma unroll
       for (int r = 0; r < 4; r++)
        rmax[i][r] = fmaxf(rmax[i][r], __shfl_xor(rmax[i][r], mk));
#pragma unroll
    for (int i = 0; i < 2; i++)
#pragma unroll
     for (int j = 0; j < 2; j++)
#pragma unroll
      for (int r = 0; r < 4; r++)
        rsum[i][r] += __expf(vv[i][j][r] - rmax[i][r]);
#pragma unroll
    for (int mk = 1; mk < 16; mk <<= 1)
#pragma unroll
      for (int i = 0; i < 2; i++)
#pragma unroll
       for (int r = 0; r < 4; r++)
        rsum[i][r] += __shfl_xor(rsum[i][r], mk);
    if (la == 0){
#pragma unroll
      for (int i = 0; i < 2; i++)
#pragma unroll
       for (int r = 0; r < 4; r++)
        pst[wv & 1][moff + 16*i + quad*4 + r] = make_float2(rmax[i][r], rsum[i][r]);
    }
    __syncthreads();
    if (t < 64){
      float2 pa = pst[0][t], pb = pst[1][t];
      float m = fmaxf(pa.x, pb.x);
      float s = pa.y*__expf(pa.x-m) + pb.y*__expf(pb.x-m);
      ((float2*)C2)[((i64)bz*16 + blockIdx.x)*1024 + m0 + t] = make_float2(m, s);
    }
    return;
  }
#pragma unroll
  for (int i = 0; i < 2; i++)
#pragma unroll
   for (int j = 0; j < 2; j++)
#pragma unroll
    for (int r = 0; r < 4; r++){
      int gm = m0 + moff + 16*i + quad*4 + r;
      int gn = n0 + noff + 16*j + la;
      i64 idx = (i64)gm*ldc + gn;
      float v = acc[i][j][r];
      if (EPI == 3){
        const float* g = (const float*)X1;
        Cb[idx] = sigf(g[(i64)gm*1536 + gn]) * v;
      } else if (EPI == 4){
        const float* am = (const float*)X1;
        const float* sg = (const float*)X2;
        float res = am[(i64)gm*768 + gn] + sigf(sg[(i64)gm*1536 + gn] * v);
        Cb[idx] = res;
        if (C2) C2[idx] = res;
      } else if (EPI == 5){
        u16* qp = (u16*)C2;
        if (gn < 768){
          qp[(i64)gm*768 + gn] = f2bu(v + bias[gn]);
        } else {
          i64 ix = (i64)gm*2304 + (gn - 768);
          Cb[ix]  = v;
          Cb2[ix] = f2bu(v);
        }
      } else {
        if (bias) v += bias[(i64)bz*sbBias + gn];
        if (Cb)  Cb[idx]  = v;
        if (Cb2) Cb2[idx] = f2bu(v);
      }
    }
}

extern "C" void kernel_launch(void* const* d_in, const int* in_sizes, int n_in,
                              void* d_out, int out_size, void* d_ws, size_t ws_size,
                              hipStream_t stream){
  const float* a_in   = (const float*)d_in[0];
  const float* s_in   = (const float*)d_in[1];
  const float* z_in   = (const float*)d_in[2];
  const float* attn_sn_w = (const float*)d_in[3];
  const float* attn_pb_w = (const float*)d_in[4];
  const float* attn_pb_b = (const float*)d_in[5];
  const float* attn_pnb_w= (const float*)d_in[6];
  const float* pair_w = (const float*)d_in[7];
  const float* pair_b = (const float*)d_in[8];
  const float* q_w    = (const float*)d_in[9];
  const float* q_b    = (const float*)d_in[10];
  const float* kvg_w  = (const float*)d_in[11];
  const float* bias_w = (const float*)d_in[12];
  const float* bias_b = (const float*)d_in[13];
  const float* ao_w   = (const float*)d_in[14];
  const float* out_w  = (const float*)d_in[15];
  const float* out_b  = (const float*)d_in[16];
  const float* tr_sn_w= (const float*)d_in[17];
  const float* tr_pb_w= (const float*)d_in[18];
  const float* tr_pb_b= (const float*)d_in[19];
  const float* tr_pnb_w=(const float*)d_in[20];
  const float* tr_a_w = (const float*)d_in[21];
  const float* tr_s_w = (const float*)d_in[22];
  const float* tr_s_b = (const float*)d_in[23];
  const float* tr_b_w = (const float*)d_in[24];

  // -------- workspace layout --------
  float* ws      = (float*)d_ws;
  float* scores  = ws;                       // 16777216 f32 [h][k][m]
  float* hbuf    = scores;                   // overlay (TRA out, post-attn)
  float* a_cur   = ws + 16777216;            // 786432
  float* AN      = a_cur + 786432;           // 786432
  float* SN0     = AN + 786432;              // 393216
  float* kvg     = SN0 + 393216;             // 2359296
  float* attnmm  = kvg + 2359296;            // 786432
  float* Pf_at   = attnmm + 786432;          // 3145728 (2 layers x [1024][1536])
  float* Pf_tr   = Pf_at + 3145728;          // 3145728
  float* gfused2 = Pf_tr + 3145728;          // 3145728
  float2* partials = (float2*)(gfused2 + 3145728);     // 524288 float2
  float2* rstats   = (float2*)((float*)partials + 1048576); // 16384 float2
  float* gbias   = (float*)rstats + 32768;   // 3072
  u16*   zcwh    = (u16*)(gbias + 3072);     // 2048 u16 (= 1024 f32)
  float* zcb     = gbias + 3072 + 1024;      // 64
  u16* wpool2    = (u16*)(zcb + 64);         // 16515072 (both layers)
  u16* SNw2      = wpool2 + 16515072;        // 1572864 (2 layers x [1024][768])
  u16* s_bf      = SNw2 + 1572864;           // 393216
  u16* a2bf      = s_bf + 393216;            // 786432
  u16* qproj_bf  = a2bf + 786432;            // 786432
  u16* kvg_bf    = qproj_bf + 786432;        // 2359296
  u16* ogated_bf = kvg_bf + 2359296;         // 786432
  u16* bbuf_bf   = ogated_bf + 786432;       // 1572864
  u16* Zp2       = bbuf_bf + 1572864;        // 33554432
  u16* Vt_h      = Zp2 + 33554432;           // 786432

  // pool offsets: PB|PNB|Q|KVG|AO|OUT|TRS|TPB|TPNB|TRA|TRB
  const i64 OFF_PB=0, OFF_Q=589824, OFF_AO=2949120,
            OFF_OUT=3538944, OFF_TPB=4128768, OFF_TRA=4718592, OFF_TRB=7077888;

  // ---------------- preamble (layer-independent, batched over layers) ----------------
  f2b<<<384,256,0,stream>>>(s_in, s_bf, 393216);
  ln_rows<<<1024,256,0,stream>>>(s_in, SN0, 384);
  prep_small<<<21,256,0,stream>>>(out_b, tr_s_b, gbias,
      pair_w, pair_b, bias_w, bias_b, zcwh, zcb);
  zln_mfma<<<4096,256,0,stream>>>(z_in, zcwh, zcb, Zp2);
  f2b_wpool<<<16128,256,0,stream>>>(attn_pb_w, attn_pnb_w, q_w, kvg_w, ao_w,
      out_w, tr_s_w, tr_pb_w, tr_pnb_w, tr_a_w, tr_b_w, wpool2);
  scale2<<<6144,256,0,stream>>>(SN0, attn_sn_w, tr_sn_w, SNw2);
  // Pf_at[l] = SNw2[l][:,0:384] @ [PB|PNB][l]^T
  gbt<0><<<dim3(24,16,2),256,0,stream>>>(SNw2,768,786432, wpool2+OFF_PB,384,POOLSZ,
      Pf_at,1536,1572864, nullptr, nullptr,0, nullptr,nullptr,nullptr, 384,1.f);
  // Pf_tr[l] = SNw2[l][:,384:768] @ [TPB|TPNB][l]^T
  gbt<0><<<dim3(24,16,2),256,0,stream>>>(SNw2+384,768,786432, wpool2+OFF_TPB,384,POOLSZ,
      Pf_tr,1536,1572864, nullptr, nullptr,0, nullptr,nullptr,nullptr, 384,1.f);
  // gfused2[l] = s_bf @ [OUT|TRS][l]^T + gbias[l]
  gbt<0><<<dim3(24,16,2),256,0,stream>>>(s_bf,384,0, wpool2+OFF_OUT,384,POOLSZ,
      gfused2,1536,1572864, nullptr, gbias,1536, nullptr,nullptr,nullptr, 384,1.f);

  // ---------------- per-layer ----------------
  for (int l = 0; l < 2; l++){
    const u16* wp = wpool2 + (i64)l*POOLSZ;
    ln_rows<<<1024,256,0,stream>>>(l == 0 ? a_in : a_cur, AN, 768);
    adaln2<<<3072,256,0,stream>>>(Pf_at + (i64)l*1572864, AN, attn_pb_b + l*768, a2bf);

    // fused Q|KVG projection (N=3072)
    gbt<5><<<dim3(48,16,1),256,0,stream>>>(a2bf,768,0, wp+OFF_Q,768,0,
        kvg,2304,0, kvg_bf, q_b + l*768,0, nullptr,nullptr, (float*)qproj_bf, 768,1.f);

    // scores = K·Q/48 + Zp; fused per-row stats partials
    gbt<1><<<dim3(16,16,16),256,0,stream>>>(kvg_bf,144,147456, qproj_bf,48,49152,
        scores,1024,1048576, nullptr, nullptr,0, Zp2 + (i64)l*16777216, nullptr,
        (float*)partials, 48, 1.f/48.f);
    stat_merge<<<64,256,0,stream>>>(partials, rstats);

    vtrans<<<dim3(16,16),256,0,stream>>>(kvg, Vt_h);
    av_gemm<<<dim3(1,16,16),256,0,stream>>>(scores, rstats, Vt_h, kvg, ogated_bf);

    // AO gemm with fused attn gate
    gbt<3><<<dim3(12,16,1),256,0,stream>>>(ogated_bf,768,0, wp+OFF_AO,768,0,
        attnmm,768,0, nullptr, nullptr,0, gfused2 + (i64)l*1572864, nullptr,nullptr, 768,1.f);

    // transition
    adaln2<<<3072,256,0,stream>>>(Pf_tr + (i64)l*1572864, AN, tr_pb_b + l*768, a2bf);
    gbt<0><<<dim3(48,16,1),256,0,stream>>>(a2bf,768,0, wp+OFF_TRA,768,0,
        hbuf,3072,0, nullptr, nullptr,0, nullptr,nullptr,nullptr, 768,1.f);
    silu_mul_bf<<<6144,256,0,stream>>>(hbuf, bbuf_bf, 1572864);

    // TRB gemm with fused final combine
    gbt<4><<<dim3(12,16,1),256,0,stream>>>(bbuf_bf,1536,0, wp+OFF_TRB,1536,0,
        a_cur,768,0, nullptr, nullptr,0, attnmm, gfused2 + (i64)l*1572864 + 768,
        (l==1) ? (float*)d_out : nullptr, 1536,1.f);
  }
}